// Round 1
// 1337.859 us; speedup vs baseline: 1.4688x; 1.4688x over previous
//
#include <hip/hip_runtime.h>
#include <hip/hip_bf16.h>
#include <math.h>

typedef __hip_bfloat16 bf16;
typedef __attribute__((ext_vector_type(4))) float f32x4;
typedef __attribute__((ext_vector_type(8))) short s16x8;
typedef __attribute__((ext_vector_type(4))) short s16x4;

static __device__ __forceinline__ float bits2f(short s){ return __uint_as_float(((unsigned)(unsigned short)s)<<16); }
static __device__ __forceinline__ short bfbits(float f){ bf16 h = __float2bfloat16(f); return *reinterpret_cast<short*>(&h); }
static __device__ __forceinline__ float ldf(float v){ return v; }
static __device__ __forceinline__ float sigm(float v){ return 1.f/(1.f+__expf(-v)); }
static __device__ __forceinline__ bf16  f2b(float v){ return __float2bfloat16(v); }

#define P_IMG 4096   // 64*64

#define GLDS16(SRC, DST) __builtin_amdgcn_global_load_lds( \
    (__attribute__((address_space(1))) void*)(SRC), \
    (__attribute__((address_space(3))) void*)(DST), 16, 0, 0)

// ---------------- workspace layout (bytes) ----------------
namespace {
constexpr long long XATT_OFF = 0;            // bf16 px-major (32,4096,256) = 64MB
constexpr long long BIG_OFF  = 67108864;     // tbuf: bf16 px-major (32,4096,256) or (32,4096,512)
constexpr long long MISC     = 134217728;
constexpr long long XM_OFF   = MISC;                 // f32 (2048,484)
constexpr long long MSUM_OFF = MISC + 3964928;       // f32 (2048,484)
constexpr long long SH_OFF   = MISC + 7929856;       // f32 (2048,946)
constexpr long long SH2_OFF  = MISC + 15679488;      // f32 (2048,946)
constexpr long long X4P_OFF  = MISC + 23429120;      // f32 (32,64,1024)
constexpr long long IDX1_OFF = MISC + 31817728;      // i32 (32,64,1024)
constexpr long long XP_OFF   = MISC + 40206336;      // f32 (32,64,256)
constexpr long long IDX2_OFF = MISC + 42303488;      // i32
constexpr long long HBUF_OFF = MISC + 44400640;      // f32 (32,64,256)
constexpr long long A1_OFF   = MISC + 46497792;
constexpr long long A2_OFF   = MISC + 48594944;
constexpr long long A1S_OFF  = MISC + 50692096;      // f32 (32,32,256)
constexpr long long A2S_OFF  = MISC + 51740672;
constexpr long long AGG_OFF  = MISC + 52789248;      // f32 (32,2,256)
constexpr long long SIG_OFF  = MISC + 52854784;
constexpr long long ATTN_OFF = MISC + 52920320;      // f32 (32,64,256)
constexpr long long H2_OFF   = MISC + 55017472;
constexpr long long XG_OFF   = MISC + 57114624;      // f32 (32,64,1024)
constexpr long long P33_OFF  = 201326592;            // f32 (32,64,4096); also hosts packed weights
constexpr long long STATS_OFF= 234881024;
constexpr long long WS_NEED  = 234897408;
}

__global__ __launch_bounds__(256) void zero_out_k(float* __restrict__ o, int n){
    int i = blockIdx.x*256 + threadIdx.x;
    if (i < n) o[i] = 0.f;
}

// ======== weight pre-pack: f32 [O][K] -> bf16 fragment-major ========
// frag layout: idx = ((((k>>6)*2 + kk)*OT16 + (o>>4))*4 + q)*16 + m16)*8 + r
// so an A-fragment load is base + lane*8 shorts (fully coalesced 1KB).
__global__ __launch_bounds__(256) void packw_k(const float* __restrict__ W, short* __restrict__ Wp,
                                               int kshift, int OT16)
{
    int i = blockIdx.x*256 + threadIdx.x;
    int o = i >> kshift;
    int k = i & ((1<<kshift)-1);
    long dest = (((((long)(k>>6)*2 + ((k>>5)&1))*OT16 + (o>>4))*4 + ((k>>3)&3))*16 + (o&15))*8 + (k&7);
    Wp[dest] = bfbits(W[i]);
}

// ======== PA expand: f32 c-major input -> bf16 px-major out (scatter staging) ========
__global__ __launch_bounds__(256) void convmfma_f32_k(
    const float* __restrict__ in, int inCtot, int inOff,
    const short* __restrict__ Wp, int K, int OT16,
    short* __restrict__ out, int outC)
{
    __shared__ __align__(16) short sB[64*64];
    const int tid = threadIdx.x;
    const int b = blockIdx.z;
    const int Mbase = blockIdx.y * 64;
    const int pxBase = blockIdx.x * 64;
    const int lane = tid & 63, w = tid >> 6;
    const int n16 = lane & 15, q = lane >> 4;
    const int wm = w >> 1, wn = w & 1;
    const int otBase = (Mbase>>4) + wm*2;

    const float* ib = in + ((long)b*inCtot + inOff)*P_IMG + pxBase;
    f32x4 zero = {0.f,0.f,0.f,0.f};
    f32x4 acc[2][2];
    acc[0][0]=zero; acc[0][1]=zero; acc[1][0]=zero; acc[1][1]=zero;
    const int pxp = (tid & 31)*2;
    const int chb = (tid >> 5)*8;

    for (int kb = 0; kb < K; kb += 64){
        __syncthreads();
        #pragma unroll
        for (int i = 0; i < 8; i++){
            int c = chb + i;
            float2 tv = *(const float2*)(ib + (long)(kb + c)*P_IMG + pxp);
            int g0 = ((c>>3) ^ (pxp & 7)) << 3;
            int g1 = ((c>>3) ^ ((pxp+1) & 7)) << 3;
            sB[pxp*64     + g0 + (c&7)] = bfbits(tv.x);
            sB[(pxp+1)*64 + g1 + (c&7)] = bfbits(tv.y);
        }
        __syncthreads();
        #pragma unroll
        for (int kk = 0; kk < 2; kk++){
            s16x8 afr[2], bfr[2];
            #pragma unroll
            for (int mt=0; mt<2; mt++)
                afr[mt] = *(const s16x8*)(Wp + ((((long)(kb>>6)*2 + kk)*OT16 + otBase + mt)*64 + lane)*8);
            #pragma unroll
            for (int nt=0; nt<2; nt++){
                int n = wn*32 + nt*16 + n16;
                int g = (kk*4 + q) ^ (n & 7);
                bfr[nt] = *(const s16x8*)&sB[n*64 + (g<<3)];
            }
            #pragma unroll
            for (int mt=0; mt<2; mt++)
                #pragma unroll
                for (int nt=0; nt<2; nt++)
                    acc[mt][nt] = __builtin_amdgcn_mfma_f32_16x16x32_bf16(afr[mt], bfr[nt], acc[mt][nt], 0, 0, 0);
        }
    }

    #pragma unroll
    for (int mt=0; mt<2; mt++){
        #pragma unroll
        for (int nt=0; nt<2; nt++){
            int px = pxBase + wn*32 + nt*16 + n16;
            int o0 = Mbase + wm*32 + mt*16 + q*4;
            s16x4 ov;
            #pragma unroll
            for (int r=0; r<4; r++) ov[r] = bfbits(acc[mt][nt][r]);
            *(s16x4*)&out[((long)b*P_IMG + px)*outC + o0] = ov;
        }
    }
}

// ======== MLP1: px-major bf16 in, global_load_lds DMA staging, px-major bf16 out ========
__global__ __launch_bounds__(256) void convmfma_dma_k(
    const short* __restrict__ in, int inCtot, int inOff,
    const short* __restrict__ Wp, int K, int OT16,
    short* __restrict__ out, int outC)
{
    __shared__ __align__(16) short sB[64*64];
    const int tid = threadIdx.x;
    const int b = blockIdx.z;
    const int Mbase = blockIdx.y * 64;
    const int pxBase = blockIdx.x * 64;
    const int lane = tid & 63, w = tid >> 6;
    const int n16 = lane & 15, q = lane >> 4;
    const int wm = w >> 1, wn = w & 1;
    const int otBase = (Mbase>>4) + wm*2;

    f32x4 zero = {0.f,0.f,0.f,0.f};
    f32x4 acc[2][2];
    acc[0][0]=zero; acc[0][1]=zero; acc[1][0]=zero; acc[1][1]=zero;

    // per-lane DMA source (inverse-swizzled so swizzled ds_read is conflict-free)
    const int drow_lo = lane >> 3;      // row within segment
    const int chunk = lane & 7;

    for (int kb = 0; kb < K; kb += 64){
        __syncthreads();
        #pragma unroll
        for (int s = 0; s < 2; s++){
            int seg = w*2 + s;
            int row = seg*8 + drow_lo;
            int kg = chunk ^ (row & 7);
            const short* src = in + ((long)b*P_IMG + pxBase + row)*inCtot + inOff + kb + kg*8;
            GLDS16(src, (char*)sB + seg*1024);
        }
        __syncthreads();
        #pragma unroll
        for (int kk = 0; kk < 2; kk++){
            s16x8 afr[2], bfr[2];
            #pragma unroll
            for (int mt=0; mt<2; mt++)
                afr[mt] = *(const s16x8*)(Wp + ((((long)(kb>>6)*2 + kk)*OT16 + otBase + mt)*64 + lane)*8);
            #pragma unroll
            for (int nt=0; nt<2; nt++){
                int n = wn*32 + nt*16 + n16;
                int g = (kk*4 + q) ^ (n & 7);
                bfr[nt] = *(const s16x8*)&sB[n*64 + (g<<3)];
            }
            #pragma unroll
            for (int mt=0; mt<2; mt++)
                #pragma unroll
                for (int nt=0; nt<2; nt++)
                    acc[mt][nt] = __builtin_amdgcn_mfma_f32_16x16x32_bf16(afr[mt], bfr[nt], acc[mt][nt], 0, 0, 0);
        }
    }

    #pragma unroll
    for (int mt=0; mt<2; mt++){
        #pragma unroll
        for (int nt=0; nt<2; nt++){
            int px = pxBase + wn*32 + nt*16 + n16;
            int o0 = Mbase + wm*32 + mt*16 + q*4;
            s16x4 ov;
            #pragma unroll
            for (int r=0; r<4; r++) ov[r] = bfbits(acc[mt][nt][r]);
            *(s16x4*)&out[((long)b*P_IMG + px)*outC + o0] = ov;
        }
    }
}

// ======== BN+ReLU convs (PA gate epi=1, MLP2 epi=2): px-major bf16 in, reg staging ========
template<int EPI, typename TOUT>
__global__ __launch_bounds__(256) void convmfma_reg_k(
    const short* __restrict__ in, int inCtot, int inOff,
    const float2* __restrict__ stats,
    const short* __restrict__ Wp, int K, int OT16,
    TOUT* __restrict__ out, int outC, int outOff,
    const float* __restrict__ aux, int auxC, int auxOff)
{
    __shared__ __align__(16) short sB[64*64];
    const int tid = threadIdx.x;
    const int b = blockIdx.z;
    const int Mbase = blockIdx.y * 64;
    const int pxBase = blockIdx.x * 64;
    const int lane = tid & 63, w = tid >> 6;
    const int n16 = lane & 15, q = lane >> 4;
    const int wm = w >> 1, wn = w & 1;
    const int otBase = (Mbase>>4) + wm*2;

    f32x4 zero = {0.f,0.f,0.f,0.f};
    f32x4 acc[2][2];
    acc[0][0]=zero; acc[0][1]=zero; acc[1][0]=zero; acc[1][1]=zero;

    const int srow = tid >> 3, schunk = tid & 7;
    const int skg = schunk ^ (srow & 7);   // same for row and row+32

    for (int kb = 0; kb < K; kb += 64){
        // stats for this thread's 8 channels (contiguous 64B)
        const f32x4* sp = (const f32x4*)(stats + kb + skg*8);
        f32x4 p0 = sp[0], p1 = sp[1], p2 = sp[2], p3 = sp[3];
        float mm[8] = {p0[0],p0[2],p1[0],p1[2],p2[0],p2[2],p3[0],p3[2]};
        float iv[8] = {p0[1],p0[3],p1[1],p1[3],p2[1],p2[3],p3[1],p3[3]};
        s16x8 stg[2];
        #pragma unroll
        for (int it = 0; it < 2; it++){
            int row = it*32 + srow;
            s16x8 rv = *(const s16x8*)(in + ((long)b*P_IMG + pxBase + row)*inCtot + inOff + kb + skg*8);
            s16x8 ov;
            #pragma unroll
            for (int j=0;j<8;j++){
                float f = bits2f(rv[j]);
                f = (f - mm[j])*iv[j];
                f = fmaxf(f, 0.f);
                ov[j] = bfbits(f);
            }
            stg[it] = ov;
        }
        __syncthreads();
        *(s16x8*)&sB[srow*64 + schunk*8]      = stg[0];
        *(s16x8*)&sB[(32+srow)*64 + schunk*8] = stg[1];
        __syncthreads();
        #pragma unroll
        for (int kk = 0; kk < 2; kk++){
            s16x8 afr[2], bfr[2];
            #pragma unroll
            for (int mt=0; mt<2; mt++)
                afr[mt] = *(const s16x8*)(Wp + ((((long)(kb>>6)*2 + kk)*OT16 + otBase + mt)*64 + lane)*8);
            #pragma unroll
            for (int nt=0; nt<2; nt++){
                int n = wn*32 + nt*16 + n16;
                int g = (kk*4 + q) ^ (n & 7);
                bfr[nt] = *(const s16x8*)&sB[n*64 + (g<<3)];
            }
            #pragma unroll
            for (int mt=0; mt<2; mt++)
                #pragma unroll
                for (int nt=0; nt<2; nt++)
                    acc[mt][nt] = __builtin_amdgcn_mfma_f32_16x16x32_bf16(afr[mt], bfr[nt], acc[mt][nt], 0, 0, 0);
        }
    }

    #pragma unroll
    for (int mt=0; mt<2; mt++){
        #pragma unroll
        for (int nt=0; nt<2; nt++){
            int px = pxBase + wn*32 + nt*16 + n16;
            int o0 = Mbase + wm*32 + mt*16 + q*4;
            if constexpr (EPI == 1){
                // out px-major bf16: v = aux * sigmoid(acc)
                s16x4 ov;
                #pragma unroll
                for (int r=0; r<4; r++){
                    float av = aux[((long)b*auxC + auxOff + o0 + r)*P_IMG + px];
                    ov[r] = bfbits(av * sigm(acc[mt][nt][r]));
                }
                *(s16x4*)&(((short*)out)[((long)b*P_IMG + px)*outC + outOff + o0]) = ov;
            } else {
                // EPI==2: out c-major f32: v = aux + acc (residual)
                #pragma unroll
                for (int r=0; r<4; r++){
                    int o = o0 + r;
                    float av = aux[((long)b*auxC + auxOff + o)*P_IMG + px];
                    out[((long)b*outC + outOff + o)*P_IMG + px] = av + acc[mt][nt][r];
                }
            }
        }
    }
}

// ============ BN batch-stats: px-major bf16 [b][4096][C] ============
template<int C>
__global__ __launch_bounds__(256) void bnstats_pm_k(const short* __restrict__ in, float* __restrict__ sums)
{
    constexpr int CH8 = C/8;
    constexpr int PL  = 256/CH8;
    __shared__ float accs[2*C];
    const int t = threadIdx.x;
    for (int i=t;i<2*C;i+=256) accs[i]=0.f;
    __syncthreads();
    const int chunk = t & (CH8-1), pl = t / CH8;
    const int b = blockIdx.y;
    float s[8], s2[8];
    #pragma unroll
    for (int j=0;j<8;j++){ s[j]=0.f; s2[j]=0.f; }
    for (int px = blockIdx.x*256 + pl; px < (blockIdx.x+1)*256; px += PL){
        s16x8 v = *(const s16x8*)&in[((long)b*P_IMG + px)*C + chunk*8];
        #pragma unroll
        for (int j=0;j<8;j++){
            float f = bits2f(v[j]);
            s[j] += f; s2[j] = fmaf(f,f,s2[j]);
        }
    }
    #pragma unroll
    for (int j=0;j<8;j++){
        atomicAdd(&accs[(chunk*8+j)*2],   s[j]);
        atomicAdd(&accs[(chunk*8+j)*2+1], s2[j]);
    }
    __syncthreads();
    for (int i=t;i<2*C;i+=256) atomicAdd(&sums[i], accs[i]);
}

// ============ BN batch-stats: c-major f32 (msum, xg) ============
template<typename T>
__global__ __launch_bounds__(256) void bnstats_k(const T* __restrict__ in, int Ctot, int cOff, int Pn,
                                                 float* __restrict__ sums)
{
    const int c = blockIdx.x;
    float s=0.f, s2=0.f;
    for (int b=0;b<32;b++){
        const T* qp = in + ((long)b*Ctot + cOff + c)*Pn;
        for (int p = blockIdx.y*256 + threadIdx.x; p < Pn; p += gridDim.y*256){
            float v = ldf(qp[p]);
            s += v; s2 = fmaf(v,v,s2);
        }
    }
    __shared__ float r1[256], r2[256];
    r1[threadIdx.x]=s; r2[threadIdx.x]=s2;
    __syncthreads();
    for (int k=128;k>0;k>>=1){
        if (threadIdx.x<k){ r1[threadIdx.x]+=r1[threadIdx.x+k]; r2[threadIdx.x]+=r2[threadIdx.x+k]; }
        __syncthreads();
    }
    if (threadIdx.x==0){ atomicAdd(&sums[2*c], r1[0]); atomicAdd(&sums[2*c+1], r2[0]); }
}

__global__ __launch_bounds__(256) void bnfin_k(const float* __restrict__ sums, float2* __restrict__ minv,
                                               int C, float invN)
{
    int c = blockIdx.x*256 + threadIdx.x;
    if (c < C){
        float m = sums[2*c]*invN;
        float var = sums[2*c+1]*invN - m*m;
        minv[c] = make_float2(m, 1.f/sqrtf(var + 1e-5f));
    }
}

// ============ LA: 3x3 conv, 64->64, pad 1 ============
__global__ __launch_bounds__(256) void la_conv3_k(const float* __restrict__ x, const float* __restrict__ w,
                                                  float* __restrict__ y)
{
    __shared__ float wsf[64*9*8];
    const int tid = threadIdx.x, og = blockIdx.y, b = blockIdx.z;
    for (int t = tid; t < 64*9*8; t += 256){
        int j = t & 7, ct = t >> 3;
        int c = ct / 9, tap = ct - 9*c;
        wsf[t] = w[((og*8 + j)*64 + c)*9 + tap];
    }
    __syncthreads();
    const int p = blockIdx.x*256 + tid;
    const int h = p >> 6, wc = p & 63;
    float acc[8];
    #pragma unroll
    for (int j=0;j<8;j++) acc[j]=0.f;
    for (int c=0;c<64;c++){
        const float* xb = x + ((long)b*256 + 64 + c)*P_IMG;
        #pragma unroll
        for (int kh=0;kh<3;kh++){
            int hh = h + kh - 1;
            if ((unsigned)hh >= 64u) continue;
            #pragma unroll
            for (int kw=0;kw<3;kw++){
                int ww = wc + kw - 1;
                if ((unsigned)ww >= 64u) continue;
                float v = xb[hh*64 + ww];
                const float* wr = &wsf[(c*9 + kh*3 + kw)*8];
                #pragma unroll
                for (int j=0;j<8;j++) acc[j] = fmaf(v, wr[j], acc[j]);
            }
        }
    }
    #pragma unroll
    for (int j=0;j<8;j++) y[((long)b*64 + og*8 + j)*P_IMG + p] = acc[j];
}

__global__ __launch_bounds__(256) void la_post_pm_k(const float* __restrict__ y, const float2* __restrict__ minv,
                                                    short* __restrict__ xatt)
{
    int i = blockIdx.x*256 + threadIdx.x;
    int px = i & 4095, og = (i >> 12) & 7, b = i >> 15;
    s16x8 ov;
    #pragma unroll
    for (int j=0;j<8;j++){
        float2 st = minv[og*8 + j];
        float v = (y[((long)b*64 + og*8 + j)*P_IMG + px] - st.x)*st.y;
        ov[j] = bfbits(fmaxf(v, 0.f));
    }
    *(s16x8*)&xatt[((long)b*P_IMG + px)*256 + 64 + og*8] = ov;
}

// ============ MRA ============
__global__ __launch_bounds__(256) void mp3_k(const float* __restrict__ x, float* __restrict__ mp){
    int i = blockIdx.x*256 + threadIdx.x;
    int b = i >> 18, c = (i >> 12) & 63, p = i & 4095;
    int h = p >> 6, wc = p & 63;
    const float* xb = x + ((long)b*256 + 128 + c)*P_IMG;
    float m = -3.4e38f;
    #pragma unroll
    for (int dh=-1; dh<=1; dh++){
        int hh = h+dh; if ((unsigned)hh>=64u) continue;
        #pragma unroll
        for (int dw=-1; dw<=1; dw++){
            int ww = wc+dw; if ((unsigned)ww>=64u) continue;
            m = fmaxf(m, xb[hh*64+ww]);
        }
    }
    mp[i] = m;
}

__global__ __launch_bounds__(256) void blur_k(const float* __restrict__ mp, float* __restrict__ xm){
    int idx = blockIdx.x*256 + threadIdx.x;
    int oj = idx % 22; int t = idx / 22; int oi = t % 22; int bc = t / 22;
    const float* mb = mp + (long)bc * P_IMG;
    const float fw[4] = {1.f,3.f,3.f,1.f};
    float s = 0.f;
    #pragma unroll
    for (int u=0;u<4;u++){
        int r = 3*oi - 1 + u;
        r = r < 0 ? -r : (r > 63 ? 126 - r : r);
        float rs = 0.f;
        #pragma unroll
        for (int v=0; v<4; v++){
            int qq = 3*oj - 1 + v;
            qq = qq < 0 ? -qq : (qq > 63 ? 126 - qq : qq);
            rs = fmaf(fw[v], mb[r*64+qq], rs);
        }
        s = fmaf(fw[u], rs, s);
    }
    xm[idx] = s * (1.f/64.f);
}

__global__ __launch_bounds__(256) void strips_k(const float* __restrict__ xm, const float* __restrict__ wh1,
                                                const float* __restrict__ wv1, float* __restrict__ msum)
{
    int idx = blockIdx.x*256 + threadIdx.x;
    int j = idx % 22; int t = idx / 22; int i = t % 22; int bc = t / 22; int c = bc & 63;
    const float* xb = xm + (long)bc*484;
    float s = 0.f;
    #pragma unroll
    for (int u=0;u<11;u++){
        int ii = i + u - 5; if ((unsigned)ii >= 22u) continue;
        #pragma unroll
        for (int v=0;v<3;v++){
            int jj = j + v - 1; if ((unsigned)jj >= 22u) continue;
            s = fmaf(wh1[c*33 + u*3 + v], xb[ii*22+jj], s);
        }
    }
    #pragma unroll
    for (int u=0;u<3;u++){
        int ii = i + u - 1; if ((unsigned)ii >= 22u) continue;
        #pragma unroll
        for (int v=0;v<11;v++){
            int jj = j + v - 5; if ((unsigned)jj >= 22u) continue;
            s = fmaf(wv1[c*33 + u*11 + v], xb[ii*22+jj], s);
        }
    }
    msum[idx] = s;
}

__global__ __launch_bounds__(256) void shearh_k(const float* __restrict__ xm, float* __restrict__ sh){
    int idx = blockIdx.x*256 + threadIdx.x;
    int j = idx % 43; int t = idx / 43; int i = t % 22; int bc = t / 22;
    int f = i*43 + j; int r = f / 44; int q = f - 44*r;
    sh[idx] = (q < 22) ? xm[(long)bc*484 + r*22 + q] : 0.f;
}

__global__ __launch_bounds__(256) void shconvh_k(const float* __restrict__ sh, const float* __restrict__ w2,
                                                 float* __restrict__ sh2)
{
    int idx = blockIdx.x*256 + threadIdx.x;
    int j = idx % 43; int t = idx / 43; int i = t % 22; int bc = t / 22; int c = bc & 63;
    const float* sb = sh + (long)bc*946;
    float s = 0.f;
    #pragma unroll
    for (int u=0;u<11;u++){
        int ii = i + u - 5; if ((unsigned)ii >= 22u) continue;
        #pragma unroll
        for (int v=0;v<3;v++){
            int jj = j + v - 1; if ((unsigned)jj >= 43u) continue;
            s = fmaf(w2[c*33 + u*3 + v], sb[ii*43+jj], s);
        }
    }
    sh2[idx] = s;
}

__global__ __launch_bounds__(256) void shaddh_k(const float* __restrict__ sh2, float* __restrict__ msum){
    int idx = blockIdx.x*256 + threadIdx.x;
    int j = idx % 22; int t = idx / 22; int i = t % 22; int bc = t / 22;
    int f = i*44 + j; int r = f / 43; int q = f - 43*r;
    msum[idx] += sh2[(long)bc*946 + r*43 + q];
}

__global__ __launch_bounds__(256) void shearv_k(const float* __restrict__ xm, float* __restrict__ sv){
    int idx = blockIdx.x*256 + threadIdx.x;
    int j = idx % 22; int t = idx / 22; int i = t % 43; int bc = t / 43;
    int g = j*43 + i; int r = g / 44; int q = g - 44*r;
    sv[idx] = (q < 22) ? xm[(long)bc*484 + q*22 + r] : 0.f;
}

__global__ __launch_bounds__(256) void shconvv_k(const float* __restrict__ sv, const float* __restrict__ wv2,
                                                 float* __restrict__ sv2)
{
    int idx = blockIdx.x*256 + threadIdx.x;
    int j = idx % 22; int t = idx / 22; int i = t % 43; int bc = t / 43; int c = bc & 63;
    const float* sb = sv + (long)bc*946;
    float s = 0.f;
    #pragma unroll
    for (int u=0;u<3;u++){
        int ii = i + u - 1; if ((unsigned)ii >= 43u) continue;
        #pragma unroll
        for (int v=0;v<11;v++){
            int jj = j + v - 5; if ((unsigned)jj >= 22u) continue;
            s = fmaf(wv2[c*33 + u*11 + v], sb[ii*22+jj], s);
        }
    }
    sv2[idx] = s;
}

__global__ __launch_bounds__(256) void shaddv_k(const float* __restrict__ sv2, float* __restrict__ msum){
    int idx = blockIdx.x*256 + threadIdx.x;
    int xcol = idx % 22; int t = idx / 22; int y = t % 22; int bc = t / 22;
    int g = xcol*44 + y; int r = g / 43; int q = g - 43*r;
    msum[idx] += sv2[(long)bc*946 + q*22 + r];
}

__global__ __launch_bounds__(256) void mra_gate_pm_k(const float* __restrict__ x, const float* __restrict__ msum,
                                                     const float2* __restrict__ minv, short* __restrict__ xatt)
{
    int i = blockIdx.x*256 + threadIdx.x;
    int px = i & 4095, og = (i >> 12) & 7, b = i >> 15;
    int h = px >> 6, wcol = px & 63;
    int ri = (h*22) >> 6, ci = (wcol*22) >> 6;
    s16x8 ov;
    #pragma unroll
    for (int j=0;j<8;j++){
        int c = og*8 + j;
        float g = msum[((long)b*64 + c)*484 + ri*22 + ci];
        float2 st = minv[c];
        g = sigm((g - st.x)*st.y);
        float xv = x[((long)b*256 + 128 + c)*P_IMG + px];
        ov[j] = bfbits(xv * g);
    }
    *(s16x8*)&xatt[((long)b*P_IMG + px)*256 + 128 + og*8] = ov;
}

// ============ GA ============
__global__ __launch_bounds__(256) void pool1_k(const float* __restrict__ x, float* __restrict__ x4p,
                                               int* __restrict__ idx1)
{
    int i = blockIdx.x*256 + threadIdx.x;
    int b = i >> 16, c = (i >> 10) & 63, s = i & 1023;
    int y = s >> 5, xc = s & 31;
    const float* xb = x + ((long)b*256 + 192 + c)*P_IMG;
    float v00 = xb[(2*y)*64 + 2*xc];
    float v01 = xb[(2*y)*64 + 2*xc + 1];
    float v10 = xb[(2*y+1)*64 + 2*xc];
    float v11 = xb[(2*y+1)*64 + 2*xc + 1];
    float best = v00; int bi = 0;
    if (v01 > best){ best = v01; bi = 1; }
    if (v10 > best){ best = v10; bi = 2; }
    if (v11 > best){ best = v11; bi = 3; }
    x4p[i] = best; idx1[i] = bi;
}

__global__ __launch_bounds__(256) void pool2_k(const float* __restrict__ x4p, float* __restrict__ xp,
                                               int* __restrict__ idx2)
{
    int i = blockIdx.x*256 + threadIdx.x;
    int b = i >> 14, c = (i >> 8) & 63, s = i & 255;
    int y = s >> 4, xc = s & 15;
    const float* xb = x4p + ((long)b*64 + c)*1024;
    float v00 = xb[(2*y)*32 + 2*xc];
    float v01 = xb[(2*y)*32 + 2*xc + 1];
    float v10 = xb[(2*y+1)*32 + 2*xc];
    float v11 = xb[(2*y+1)*32 + 2*xc + 1];
    float best = v00; int bi = 0;
    if (v01 > best){ best = v01; bi = 1; }
    if (v10 > best){ best = v10; bi = 2; }
    if (v11 > best){ best = v11; bi = 3; }
    xp[i] = best; idx2[i] = bi;
}

__global__ __launch_bounds__(256) void ga_proj_k(const float* __restrict__ in, const float* __restrict__ mul,
                                                 const float* __restrict__ w, const float* __restrict__ bias,
                                                 float* __restrict__ out, int Cout, int relu)
{
    int s = threadIdx.x, og = blockIdx.x, b = blockIdx.y;
    float acc[8];
    #pragma unroll
    for (int j=0;j<8;j++) acc[j]=0.f;
    for (int c=0;c<64;c++){
        float v = in[((long)b*64 + c)*256 + s];
        if (mul) v *= mul[((long)b*64 + c)*256 + s];
        #pragma unroll
        for (int j=0;j<8;j++) acc[j] = fmaf(v, w[(og*8 + j)*64 + c], acc[j]);
    }
    #pragma unroll
    for (int j=0;j<8;j++){
        int o = og*8 + j;
        float val = acc[j] + bias[o];
        if (relu) val = fmaxf(val, 0.f);
        out[((long)b*Cout + o)*256 + s] = val;
    }
}

__global__ __launch_bounds__(256) void ga_dw5_k(const float* __restrict__ h, const float* __restrict__ w,
                                                const float* __restrict__ bias, float* __restrict__ a1)
{
    int i = blockIdx.x*256 + threadIdx.x;
    int b = i >> 14, c = (i >> 8) & 63, s = i & 255;
    int y = s >> 4, x = s & 15;
    const float* hb = h + ((long)b*64 + c)*256;
    float acc = bias[c];
    #pragma unroll
    for (int u=0;u<5;u++){
        int yy = y + u - 2; if ((unsigned)yy >= 16u) continue;
        #pragma unroll
        for (int v=0;v<5;v++){
            int xx = x + v - 2; if ((unsigned)xx >= 16u) continue;
            acc = fmaf(w[c*25 + u*5 + v], hb[yy*16 + xx], acc);
        }
    }
    a1[i] = acc;
}

__global__ __launch_bounds__(256) void ga_dw7_k(const float* __restrict__ a1, const float* __restrict__ w,
                                                const float* __restrict__ bias, float* __restrict__ a2)
{
    int i = blockIdx.x*256 + threadIdx.x;
    int b = i >> 14, c = (i >> 8) & 63, s = i & 255;
    int y = s >> 4, x = s & 15;
    const float* ab = a1 + ((long)b*64 + c)*256;
    float acc = bias[c];
    #pragma unroll
    for (int u=0;u<7;u++){
        int yy = y + 3*(u-3); if ((unsigned)yy >= 16u) continue;
        #pragma unroll
        for (int v=0;v<7;v++){
            int xx = x + 3*(v-3); if ((unsigned)xx >= 16u) continue;
            acc = fmaf(w[c*49 + u*7 + v], ab[yy*16 + xx], acc);
        }
    }
    a2[i] = acc;
}

__global__ __launch_bounds__(256) void ga_agg_k(const float* __restrict__ a1s, const float* __restrict__ a2s,
                                                float* __restrict__ agg)
{
    int i = blockIdx.x*256 + threadIdx.x;
    int b = i >> 8, s = i & 255;
    float sum = 0.f, mx = -3.4e38f;
    for (int c=0;c<32;c++){
        float v = a1s[((long)b*32 + c)*256 + s];
        sum += v; mx = fmaxf(mx, v);
    }
    for (int c=0;c<32;c++){
        float v = a2s[((long)b*32 + c)*256 + s];
        sum += v; mx = fmaxf(mx, v);
    }
    agg[((long)b*2 + 0)*256 + s] = sum * (1.f/64.f);
    agg[((long)b*2 + 1)*256 + s] = mx;
}

__global__ __launch_bounds__(256) void ga_sq_k(const float* __restrict__ agg, const float* __restrict__ w,
                                               const float* __restrict__ bias, float* __restrict__ sig)
{
    int i = blockIdx.x*256 + threadIdx.x;
    int b = i >> 9, o = (i >> 8) & 1, s = i & 255;
    int y = s >> 4, x = s & 15;
    float acc = bias[o];
    for (int ic=0; ic<2; ic++){
        const float* ab = agg + ((long)b*2 + ic)*256;
        #pragma unroll
        for (int u=0;u<7;u++){
            int yy = y + u - 3; if ((unsigned)yy >= 16u) continue;
            #pragma unroll
            for (int v=0;v<7;v++){
                int xx = x + v - 3; if ((unsigned)xx >= 16u) continue;
                acc = fmaf(w[((o*2 + ic)*7 + u)*7 + v], ab[yy*16 + xx], acc);
            }
        }
    }
    sig[i] = sigm(acc);
}

__global__ __launch_bounds__(256) void ga_attn_k(const float* __restrict__ a1s, const float* __restrict__ a2s,
                                                 const float* __restrict__ sig, const float* __restrict__ w,
                                                 const float* __restrict__ bias, float* __restrict__ attn)
{
    int s = threadIdx.x, og = blockIdx.x, b = blockIdx.y;
    float s0 = sig[((long)b*2 + 0)*256 + s];
    float s1 = sig[((long)b*2 + 1)*256 + s];
    float acc[8];
    #pragma unroll
    for (int j=0;j<8;j++) acc[j]=0.f;
    for (int c=0;c<32;c++){
        float v = a1s[((long)b*32 + c)*256 + s]*s0 + a2s[((long)b*32 + c)*256 + s]*s1;
        #pragma unroll
        for (int j=0;j<8;j++) acc[j] = fmaf(v, w[(og*8 + j)*32 + c], acc[j]);
    }
    #pragma unroll
    for (int j=0;j<8;j++){
        int o = og*8 + j;
        attn[((long)b*64 + o)*256 + s] = acc[j] + bias[o];
    }
}

__global__ __launch_bounds__(256) void ga_unpool1_k(const float* __restrict__ h2, const int* __restrict__ idx2,
                                                    float* __restrict__ xg)
{
    int i = blockIdx.x*256 + threadIdx.x;
    int b = i >> 16, c = (i >> 10) & 63, s = i & 1023;
    int Y = s >> 5, X = s & 31;
    int slot = ((Y & 1) << 1) | (X & 1);
    long pi = ((long)b*64 + c)*256 + (Y >> 1)*16 + (X >> 1);
    xg[i] = (idx2[pi] == slot) ? h2[pi] : 0.f;
}

__global__ __launch_bounds__(256) void ga_out_pm_k(const float* __restrict__ xg, const int* __restrict__ idx1,
                                                   const float2* __restrict__ minv, short* __restrict__ xatt)
{
    int i = blockIdx.x*256 + threadIdx.x;
    int px = i & 4095, og = (i >> 12) & 7, b = i >> 15;
    int hh = px >> 6, ww = px & 63;
    int slot = ((hh & 1) << 1) | (ww & 1);
    s16x8 ov;
    #pragma unroll
    for (int j=0;j<8;j++){
        int c = og*8 + j;
        long pi = ((long)b*64 + c)*1024 + (hh >> 1)*32 + (ww >> 1);
        float v = 0.f;
        if (idx1[pi] == slot){
            float2 st = minv[c];
            v = (xg[pi] - st.x)*st.y;
        }
        ov[j] = bfbits(v);
    }
    *(s16x8*)&xatt[((long)b*P_IMG + px)*256 + 192 + og*8] = ov;
}

// ============================================================================
extern "C" void kernel_launch(void* const* d_in, const int* in_sizes, int n_in,
                              void* d_out, int out_size, void* d_ws, size_t ws_size,
                              hipStream_t stream)
{
    const float* x      = (const float*)d_in[0];
    const float* pa_w1  = (const float*)d_in[1];
    const float* pa_w2  = (const float*)d_in[2];
    const float* la_w   = (const float*)d_in[3];
    const float* mra_h1 = (const float*)d_in[4];
    const float* mra_v1 = (const float*)d_in[5];
    const float* mra_h2 = (const float*)d_in[6];
    const float* mra_v2 = (const float*)d_in[7];
    const float* g_p1w  = (const float*)d_in[8];
    const float* g_p1b  = (const float*)d_in[9];
    const float* g_c0w  = (const float*)d_in[10];
    const float* g_c0b  = (const float*)d_in[11];
    const float* g_spw  = (const float*)d_in[12];
    const float* g_spb  = (const float*)d_in[13];
    const float* g_c1w  = (const float*)d_in[14];
    const float* g_c1b  = (const float*)d_in[15];
    const float* g_c2w  = (const float*)d_in[16];
    const float* g_c2b  = (const float*)d_in[17];
    const float* g_cw   = (const float*)d_in[18];
    const float* g_cb   = (const float*)d_in[19];
    const float* g_sqw  = (const float*)d_in[20];
    const float* g_sqb  = (const float*)d_in[21];
    const float* g_p2w  = (const float*)d_in[22];
    const float* g_p2b  = (const float*)d_in[23];
    const float* mlp_w1 = (const float*)d_in[24];
    const float* mlp_w2 = (const float*)d_in[25];
    float* outp = (float*)d_out;
    char* ws = (char*)d_ws;

    if (ws_size < (size_t)WS_NEED){
        zero_out_k<<<(out_size + 255)/256, 256, 0, stream>>>(outp, out_size);
        return;
    }

    short* xatt = (short*)(ws + XATT_OFF);   // bf16 px-major (32,4096,256)
    short* tbuf = (short*)(ws + BIG_OFF);    // bf16 px-major (32,4096,256/512)
    float* xm   = (float*)(ws + XM_OFF);
    float* msum = (float*)(ws + MSUM_OFF);
    float* sh   = (float*)(ws + SH_OFF);
    float* sh2  = (float*)(ws + SH2_OFF);
    float* x4p  = (float*)(ws + X4P_OFF);
    int*   idx1 = (int*)(ws + IDX1_OFF);
    float* xp   = (float*)(ws + XP_OFF);
    int*   idx2 = (int*)(ws + IDX2_OFF);
    float* hbuf = (float*)(ws + HBUF_OFF);
    float* a1   = (float*)(ws + A1_OFF);
    float* a2   = (float*)(ws + A2_OFF);
    float* a1s  = (float*)(ws + A1S_OFF);
    float* a2s  = (float*)(ws + A2S_OFF);
    float* agg  = (float*)(ws + AGG_OFF);
    float* sig  = (float*)(ws + SIG_OFF);
    float* attn = (float*)(ws + ATTN_OFF);
    float* h2   = (float*)(ws + H2_OFF);
    float* xg   = (float*)(ws + XG_OFF);
    float* p33  = (float*)(ws + P33_OFF);
    float* raw  = (float*)(ws + STATS_OFF);
    float*  raw_pa  = raw;
    float*  raw_la  = raw + 512;
    float*  raw_mra = raw + 640;
    float*  raw_ga  = raw + 768;
    float*  raw_mlp = raw + 896;
    float2* mv_pa   = (float2*)(raw + 1920);
    float2* mv_la   = mv_pa + 256;
    float2* mv_mra  = mv_la + 64;
    float2* mv_ga   = mv_mra + 64;
    float2* mv_mlp  = mv_ga + 64;

    hipMemsetAsync(raw, 0, 1920*sizeof(float), stream);

    // ---- PA ---- (packed weights live in the p33 region, dead until la_conv3)
    short* wp_pa1 = (short*)(ws + P33_OFF);          // 256*64
    short* wp_pa2 = wp_pa1 + 256*64;                 // 64*256
    packw_k<<<64,256,0,stream>>>(pa_w1, wp_pa1, 6, 16);
    packw_k<<<64,256,0,stream>>>(pa_w2, wp_pa2, 8, 4);
    convmfma_f32_k<<<dim3(64,4,32),256,0,stream>>>(x,256,0, wp_pa1,64,16, tbuf,256);
    bnstats_pm_k<256><<<dim3(16,32),256,0,stream>>>(tbuf, raw_pa);
    bnfin_k<<<1,256,0,stream>>>(raw_pa, mv_pa, 256, 1.f/131072.f);
    convmfma_reg_k<1,short><<<dim3(64,1,32),256,0,stream>>>(tbuf,256,0, mv_pa, wp_pa2,256,4,
                                                            xatt,256,0, x,256,0);

    // ---- LA ----
    la_conv3_k<<<dim3(16,8,32),256,0,stream>>>(x, la_w, p33);
    bnstats_k<float><<<dim3(64,16),256,0,stream>>>(p33,64,0,4096, raw_la);
    bnfin_k<<<1,256,0,stream>>>(raw_la, mv_la, 64, 1.f/131072.f);
    la_post_pm_k<<<4096,256,0,stream>>>(p33, mv_la, xatt);

    // ---- MRA ---- (p33 reused as maxpool3 buffer)
    mp3_k<<<32768,256,0,stream>>>(x, p33);
    blur_k<<<3872,256,0,stream>>>(p33, xm);
    strips_k<<<3872,256,0,stream>>>(xm, mra_h1, mra_v1, msum);
    shearh_k<<<7568,256,0,stream>>>(xm, sh);
    shconvh_k<<<7568,256,0,stream>>>(sh, mra_h2, sh2);
    shaddh_k<<<3872,256,0,stream>>>(sh2, msum);
    shearv_k<<<7568,256,0,stream>>>(xm, sh);
    shconvv_k<<<7568,256,0,stream>>>(sh, mra_v2, sh2);
    shaddv_k<<<3872,256,0,stream>>>(sh2, msum);
    bnstats_k<float><<<dim3(64,2),256,0,stream>>>(msum,64,0,484, raw_mra);
    bnfin_k<<<1,256,0,stream>>>(raw_mra, mv_mra, 64, 1.f/15488.f);
    mra_gate_pm_k<<<4096,256,0,stream>>>(x, msum, mv_mra, xatt);

    // ---- GA ----
    pool1_k<<<8192,256,0,stream>>>(x, x4p, idx1);
    pool2_k<<<2048,256,0,stream>>>(x4p, xp, idx2);
    ga_proj_k<<<dim3(8,32),256,0,stream>>>(xp, nullptr, g_p1w, g_p1b, hbuf, 64, 1);
    ga_dw5_k<<<2048,256,0,stream>>>(hbuf, g_c0w, g_c0b, a1);
    ga_dw7_k<<<2048,256,0,stream>>>(a1, g_spw, g_spb, a2);
    ga_proj_k<<<dim3(4,32),256,0,stream>>>(a1, nullptr, g_c1w, g_c1b, a1s, 32, 0);
    ga_proj_k<<<dim3(4,32),256,0,stream>>>(a2, nullptr, g_c2w, g_c2b, a2s, 32, 0);
    ga_agg_k<<<32,256,0,stream>>>(a1s, a2s, agg);
    ga_sq_k<<<64,256,0,stream>>>(agg, g_sqw, g_sqb, sig);
    ga_attn_k<<<dim3(8,32),256,0,stream>>>(a1s, a2s, sig, g_cw, g_cb, attn);
    ga_proj_k<<<dim3(8,32),256,0,stream>>>(hbuf, attn, g_p2w, g_p2b, h2, 64, 0);
    ga_unpool1_k<<<8192,256,0,stream>>>(h2, idx2, xg);
    bnstats_k<float><<<dim3(64,4),256,0,stream>>>(xg,64,0,1024, raw_ga);
    bnfin_k<<<1,256,0,stream>>>(raw_ga, mv_ga, 64, 1.f/32768.f);
    ga_out_pm_k<<<4096,256,0,stream>>>(xg, idx1, mv_ga, xatt);

    // ---- MLP residual ---- (p33 region dead again -> host packed MLP weights)
    short* wm1 = (short*)(ws + P33_OFF);             // 512*256
    short* wm2 = wm1 + 512*256;                      // 256*512
    packw_k<<<512,256,0,stream>>>(mlp_w1, wm1, 8, 32);
    packw_k<<<512,256,0,stream>>>(mlp_w2, wm2, 9, 16);
    convmfma_dma_k<<<dim3(64,8,32),256,0,stream>>>(xatt,256,0, wm1,256,32, tbuf,512);
    bnstats_pm_k<512><<<dim3(16,32),256,0,stream>>>(tbuf, raw_mlp);
    bnfin_k<<<2,256,0,stream>>>(raw_mlp, mv_mlp, 512, 1.f/131072.f);
    convmfma_reg_k<2,float><<<dim3(64,4,32),256,0,stream>>>(tbuf,512,0, mv_mlp, wm2,512,16,
                                                            outp,256,0, x,256,0);
}

// Round 2
// 1048.466 us; speedup vs baseline: 1.8743x; 1.2760x over previous
//
#include <hip/hip_runtime.h>
#include <hip/hip_bf16.h>
#include <math.h>

typedef __hip_bfloat16 bf16;
typedef __attribute__((ext_vector_type(4))) float f32x4;
typedef __attribute__((ext_vector_type(8))) short s16x8;
typedef __attribute__((ext_vector_type(4))) short s16x4;

static __device__ __forceinline__ float bits2f(short s){ return __uint_as_float(((unsigned)(unsigned short)s)<<16); }
static __device__ __forceinline__ short bfbits(float f){ bf16 h = __float2bfloat16(f); return *reinterpret_cast<short*>(&h); }
static __device__ __forceinline__ float ldf(float v){ return v; }
static __device__ __forceinline__ float sigm(float v){ return 1.f/(1.f+__expf(-v)); }

#define P_IMG 4096   // 64*64

#define GLDS16(SRC, DST) __builtin_amdgcn_global_load_lds( \
    (__attribute__((address_space(1))) void*)(SRC), \
    (__attribute__((address_space(3))) void*)(DST), 16, 0, 0)

// ---------------- workspace layout (bytes) ----------------
namespace {
constexpr long long XATT_OFF = 0;            // bf16 px-major (32,4096,256) = 64MB
constexpr long long BIG_OFF  = 67108864;     // tbuf: bf16 px-major (32,4096,256) or (32,4096,512)
constexpr long long MISC     = 134217728;
constexpr long long XM_OFF   = MISC;                 // f32 (2048,484)
constexpr long long MSUM_OFF = MISC + 3964928;       // f32 (2048,484)
constexpr long long SH_OFF   = MISC + 7929856;       // f32 (2048,946)
constexpr long long SH2_OFF  = MISC + 15679488;      // f32 (2048,946)
constexpr long long X4P_OFF  = MISC + 23429120;      // f32 (32,64,1024)
constexpr long long IDX1_OFF = MISC + 31817728;      // i32 (32,64,1024)
constexpr long long XP_OFF   = MISC + 40206336;      // f32 (32,64,256)
constexpr long long IDX2_OFF = MISC + 42303488;      // i32
constexpr long long HBUF_OFF = MISC + 44400640;      // f32 (32,64,256)
constexpr long long A1_OFF   = MISC + 46497792;
constexpr long long A2_OFF   = MISC + 48594944;
constexpr long long A1S_OFF  = MISC + 50692096;      // f32 (32,32,256)
constexpr long long A2S_OFF  = MISC + 51740672;
constexpr long long AGG_OFF  = MISC + 52789248;      // f32 (32,2,256)
constexpr long long SIG_OFF  = MISC + 52854784;
constexpr long long ATTN_OFF = MISC + 52920320;      // f32 (32,64,256)
constexpr long long H2_OFF   = MISC + 55017472;
constexpr long long XG_OFF   = MISC + 57114624;      // f32 (32,64,1024)
constexpr long long P33_OFF  = 201326592;            // f32 (32,64,4096); also hosts packed weights
constexpr long long STATS_OFF= 234881024;
constexpr long long WS_NEED  = 234897408;
// transient (PA/LA phase only, dead once MRA starts): xpm + y_la live in MISC region
constexpr long long XPM_OFF  = MISC;                 // bf16 (32,4096,128) = 32MB
constexpr long long YLA_OFF  = MISC + 33554432;      // bf16 (32,4096,64) = 16MB
}

__global__ __launch_bounds__(256) void zero_out_k(float* __restrict__ o, int n){
    int i = blockIdx.x*256 + threadIdx.x;
    if (i < n) o[i] = 0.f;
}

// ======== weight pre-pack: f32 [O][K] -> bf16 fragment-major ========
// frag layout: idx = ((((k>>6)*2 + kk)*OT16 + (o>>4))*4 + q)*16 + m16)*8 + r
__global__ __launch_bounds__(256) void packw_k(const float* __restrict__ W, short* __restrict__ Wp,
                                               int kshift, int OT16)
{
    int i = blockIdx.x*256 + threadIdx.x;
    int o = i >> kshift;
    int k = i & ((1<<kshift)-1);
    long dest = (((((long)(k>>6)*2 + ((k>>5)&1))*OT16 + (o>>4))*4 + ((k>>3)&3))*16 + (o&15))*8 + (k&7);
    Wp[dest] = bfbits(W[i]);
}

// LA weights (64,64,9) o,c,tap -> packed with k = tap*64 + c, K=576, OT16=4
__global__ __launch_bounds__(256) void packw_la_k(const float* __restrict__ W, short* __restrict__ Wp)
{
    int i = blockIdx.x*256 + threadIdx.x;   // 64*576 = 36864
    int o = i / 576, k = i - o*576;
    int tap = k >> 6, c = k & 63;
    long dest = (((((long)(k>>6)*2 + ((k>>5)&1))*4 + (o>>4))*4 + ((k>>3)&3))*16 + (o&15))*8 + (k&7);
    Wp[dest] = bfbits(W[(o*64 + c)*9 + tap]);
}

// ======== transpose x[b][0..128][px] f32 -> xpm[b][px][128] bf16 ========
__global__ __launch_bounds__(256) void xpose_pm_k(const float* __restrict__ x, short* __restrict__ xpm)
{
    int i = blockIdx.x*256 + threadIdx.x;   // 32*16*4096
    int px = i & 4095, og = (i >> 12) & 15, b = i >> 16;
    s16x8 ov;
    #pragma unroll
    for (int j=0;j<8;j++)
        ov[j] = bfbits(x[((long)b*256 + og*8 + j)*P_IMG + px]);
    *(s16x8*)&xpm[((long)b*P_IMG + px)*128 + og*8] = ov;
}

// ======== generic 1x1 MFMA conv, px-major bf16 in, global_load_lds staging ========
__global__ __launch_bounds__(256) void convmfma_dma_k(
    const short* __restrict__ in, int inCtot, int inOff,
    const short* __restrict__ Wp, int K, int OT16,
    short* __restrict__ out, int outC)
{
    __shared__ __align__(16) short sB[64*64];
    const int tid = threadIdx.x;
    const int b = blockIdx.z;
    const int Mbase = blockIdx.y * 64;
    const int pxBase = blockIdx.x * 64;
    const int lane = tid & 63, w = tid >> 6;
    const int n16 = lane & 15, q = lane >> 4;
    const int wm = w >> 1, wn = w & 1;
    const int otBase = (Mbase>>4) + wm*2;

    f32x4 zero = {0.f,0.f,0.f,0.f};
    f32x4 acc[2][2];
    acc[0][0]=zero; acc[0][1]=zero; acc[1][0]=zero; acc[1][1]=zero;

    const int drow_lo = lane >> 3;
    const int chunk = lane & 7;

    for (int kb = 0; kb < K; kb += 64){
        __syncthreads();
        #pragma unroll
        for (int s = 0; s < 2; s++){
            int seg = w*2 + s;
            int row = seg*8 + drow_lo;
            int kg = chunk ^ (row & 7);
            const short* src = in + ((long)b*P_IMG + pxBase + row)*inCtot + inOff + kb + kg*8;
            GLDS16(src, (char*)sB + seg*1024);
        }
        __syncthreads();
        #pragma unroll
        for (int kk = 0; kk < 2; kk++){
            s16x8 afr[2], bfr[2];
            #pragma unroll
            for (int mt=0; mt<2; mt++)
                afr[mt] = *(const s16x8*)(Wp + ((((long)(kb>>6)*2 + kk)*OT16 + otBase + mt)*64 + lane)*8);
            #pragma unroll
            for (int nt=0; nt<2; nt++){
                int n = wn*32 + nt*16 + n16;
                int g = (kk*4 + q) ^ (n & 7);
                bfr[nt] = *(const s16x8*)&sB[n*64 + (g<<3)];
            }
            #pragma unroll
            for (int mt=0; mt<2; mt++)
                #pragma unroll
                for (int nt=0; nt<2; nt++)
                    acc[mt][nt] = __builtin_amdgcn_mfma_f32_16x16x32_bf16(afr[mt], bfr[nt], acc[mt][nt], 0, 0, 0);
        }
    }

    #pragma unroll
    for (int mt=0; mt<2; mt++){
        #pragma unroll
        for (int nt=0; nt<2; nt++){
            int px = pxBase + wn*32 + nt*16 + n16;
            int o0 = Mbase + wm*32 + mt*16 + q*4;
            s16x4 ov;
            #pragma unroll
            for (int r=0; r<4; r++) ov[r] = bfbits(acc[mt][nt][r]);
            *(s16x4*)&out[((long)b*P_IMG + px)*outC + o0] = ov;
        }
    }
}

// ======== LA 3x3 conv as implicit GEMM: K = 9 taps x 64 ch ========
// block = one image row (64 px) x 64 out-ch; staging reg-loads with border zero-fill.
__global__ __launch_bounds__(256) void la_mfma_k(
    const short* __restrict__ xpm,   // [b][4096][128], LA slice at +64
    const short* __restrict__ Wp,    // packed K=576, OT16=4
    short* __restrict__ y)           // [b][4096][64] bf16
{
    __shared__ __align__(16) short sB[64*64];
    const int tid = threadIdx.x;
    const int b = blockIdx.z;
    const int hRow = blockIdx.x;
    const int pxBase = hRow*64;
    const int lane = tid & 63, w = tid >> 6;
    const int n16 = lane & 15, q = lane >> 4;
    const int wm = w >> 1, wn = w & 1;
    const int otBase = wm*2;

    f32x4 zero = {0.f,0.f,0.f,0.f};
    f32x4 acc[2][2];
    acc[0][0]=zero; acc[0][1]=zero; acc[1][0]=zero; acc[1][1]=zero;

    const int srow = tid >> 3, schunk = tid & 7;

    for (int tap = 0; tap < 9; tap++){
        const int hh = hRow + (tap/3) - 1;
        const int dw = (tap%3) - 1;
        const bool hok = (unsigned)hh < 64u;
        s16x8 stg[2];
        #pragma unroll
        for (int it = 0; it < 2; it++){
            int row = it*32 + srow;          // = wc within the row-tile
            int ww = row + dw;
            int kg = schunk ^ (row & 7);
            s16x8 v = {0,0,0,0,0,0,0,0};
            if (hok && (unsigned)ww < 64u)
                v = *(const s16x8*)(xpm + ((long)b*P_IMG + hh*64 + ww)*128 + 64 + kg*8);
            stg[it] = v;
        }
        __syncthreads();
        *(s16x8*)&sB[srow*64 + schunk*8]      = stg[0];
        *(s16x8*)&sB[(32+srow)*64 + schunk*8] = stg[1];
        __syncthreads();
        #pragma unroll
        for (int kk = 0; kk < 2; kk++){
            s16x8 afr[2], bfr[2];
            #pragma unroll
            for (int mt=0; mt<2; mt++)
                afr[mt] = *(const s16x8*)(Wp + ((((long)tap*2 + kk)*4 + otBase + mt)*64 + lane)*8);
            #pragma unroll
            for (int nt=0; nt<2; nt++){
                int n = wn*32 + nt*16 + n16;
                int g = (kk*4 + q) ^ (n & 7);
                bfr[nt] = *(const s16x8*)&sB[n*64 + (g<<3)];
            }
            #pragma unroll
            for (int mt=0; mt<2; mt++)
                #pragma unroll
                for (int nt=0; nt<2; nt++)
                    acc[mt][nt] = __builtin_amdgcn_mfma_f32_16x16x32_bf16(afr[mt], bfr[nt], acc[mt][nt], 0, 0, 0);
        }
    }

    #pragma unroll
    for (int mt=0; mt<2; mt++){
        #pragma unroll
        for (int nt=0; nt<2; nt++){
            int px = pxBase + wn*32 + nt*16 + n16;
            int o0 = wm*32 + mt*16 + q*4;
            s16x4 ov;
            #pragma unroll
            for (int r=0; r<4; r++) ov[r] = bfbits(acc[mt][nt][r]);
            *(s16x4*)&y[((long)b*P_IMG + px)*64 + o0] = ov;
        }
    }
}

// ======== BN+ReLU convs (PA gate epi=1, MLP2 epi=2): px-major bf16 in, reg staging ========
template<int EPI, typename TOUT>
__global__ __launch_bounds__(256) void convmfma_reg_k(
    const short* __restrict__ in, int inCtot, int inOff,
    const float2* __restrict__ stats,
    const short* __restrict__ Wp, int K, int OT16,
    TOUT* __restrict__ out, int outC, int outOff,
    const float* __restrict__ aux, int auxC, int auxOff)
{
    __shared__ __align__(16) short sB[64*64];
    const int tid = threadIdx.x;
    const int b = blockIdx.z;
    const int Mbase = blockIdx.y * 64;
    const int pxBase = blockIdx.x * 64;
    const int lane = tid & 63, w = tid >> 6;
    const int n16 = lane & 15, q = lane >> 4;
    const int wm = w >> 1, wn = w & 1;
    const int otBase = (Mbase>>4) + wm*2;

    f32x4 zero = {0.f,0.f,0.f,0.f};
    f32x4 acc[2][2];
    acc[0][0]=zero; acc[0][1]=zero; acc[1][0]=zero; acc[1][1]=zero;

    const int srow = tid >> 3, schunk = tid & 7;
    const int skg = schunk ^ (srow & 7);

    for (int kb = 0; kb < K; kb += 64){
        const f32x4* sp = (const f32x4*)(stats + kb + skg*8);
        f32x4 p0 = sp[0], p1 = sp[1], p2 = sp[2], p3 = sp[3];
        float mm[8] = {p0[0],p0[2],p1[0],p1[2],p2[0],p2[2],p3[0],p3[2]};
        float iv[8] = {p0[1],p0[3],p1[1],p1[3],p2[1],p2[3],p3[1],p3[3]};
        s16x8 stg[2];
        #pragma unroll
        for (int it = 0; it < 2; it++){
            int row = it*32 + srow;
            s16x8 rv = *(const s16x8*)(in + ((long)b*P_IMG + pxBase + row)*inCtot + inOff + kb + skg*8);
            s16x8 ov;
            #pragma unroll
            for (int j=0;j<8;j++){
                float f = bits2f(rv[j]);
                f = (f - mm[j])*iv[j];
                f = fmaxf(f, 0.f);
                ov[j] = bfbits(f);
            }
            stg[it] = ov;
        }
        __syncthreads();
        *(s16x8*)&sB[srow*64 + schunk*8]      = stg[0];
        *(s16x8*)&sB[(32+srow)*64 + schunk*8] = stg[1];
        __syncthreads();
        #pragma unroll
        for (int kk = 0; kk < 2; kk++){
            s16x8 afr[2], bfr[2];
            #pragma unroll
            for (int mt=0; mt<2; mt++)
                afr[mt] = *(const s16x8*)(Wp + ((((long)(kb>>6)*2 + kk)*OT16 + otBase + mt)*64 + lane)*8);
            #pragma unroll
            for (int nt=0; nt<2; nt++){
                int n = wn*32 + nt*16 + n16;
                int g = (kk*4 + q) ^ (n & 7);
                bfr[nt] = *(const s16x8*)&sB[n*64 + (g<<3)];
            }
            #pragma unroll
            for (int mt=0; mt<2; mt++)
                #pragma unroll
                for (int nt=0; nt<2; nt++)
                    acc[mt][nt] = __builtin_amdgcn_mfma_f32_16x16x32_bf16(afr[mt], bfr[nt], acc[mt][nt], 0, 0, 0);
        }
    }

    #pragma unroll
    for (int mt=0; mt<2; mt++){
        #pragma unroll
        for (int nt=0; nt<2; nt++){
            int px = pxBase + wn*32 + nt*16 + n16;
            int o0 = Mbase + wm*32 + mt*16 + q*4;
            if constexpr (EPI == 1){
                s16x4 ov;
                #pragma unroll
                for (int r=0; r<4; r++){
                    float av = aux[((long)b*auxC + auxOff + o0 + r)*P_IMG + px];
                    ov[r] = bfbits(av * sigm(acc[mt][nt][r]));
                }
                *(s16x4*)&(((short*)out)[((long)b*P_IMG + px)*outC + outOff + o0]) = ov;
            } else {
                #pragma unroll
                for (int r=0; r<4; r++){
                    int o = o0 + r;
                    float av = aux[((long)b*auxC + auxOff + o)*P_IMG + px];
                    out[((long)b*outC + outOff + o)*P_IMG + px] = av + acc[mt][nt][r];
                }
            }
        }
    }
}

// ============ BN batch-stats: px-major bf16 [b][4096][C] ============
template<int C>
__global__ __launch_bounds__(256) void bnstats_pm_k(const short* __restrict__ in, float* __restrict__ sums)
{
    constexpr int CH8 = C/8;
    constexpr int PL  = 256/CH8;
    __shared__ float accs[2*C];
    const int t = threadIdx.x;
    for (int i=t;i<2*C;i+=256) accs[i]=0.f;
    __syncthreads();
    const int chunk = t & (CH8-1), pl = t / CH8;
    const int b = blockIdx.y;
    float s[8], s2[8];
    #pragma unroll
    for (int j=0;j<8;j++){ s[j]=0.f; s2[j]=0.f; }
    for (int px = blockIdx.x*256 + pl; px < (blockIdx.x+1)*256; px += PL){
        s16x8 v = *(const s16x8*)&in[((long)b*P_IMG + px)*C + chunk*8];
        #pragma unroll
        for (int j=0;j<8;j++){
            float f = bits2f(v[j]);
            s[j] += f; s2[j] = fmaf(f,f,s2[j]);
        }
    }
    #pragma unroll
    for (int j=0;j<8;j++){
        atomicAdd(&accs[(chunk*8+j)*2],   s[j]);
        atomicAdd(&accs[(chunk*8+j)*2+1], s2[j]);
    }
    __syncthreads();
    for (int i=t;i<2*C;i+=256) atomicAdd(&sums[i], accs[i]);
}

// ============ BN batch-stats: c-major f32 (msum, xg) ============
template<typename T>
__global__ __launch_bounds__(256) void bnstats_k(const T* __restrict__ in, int Ctot, int cOff, int Pn,
                                                 float* __restrict__ sums)
{
    const int c = blockIdx.x;
    float s=0.f, s2=0.f;
    for (int b=0;b<32;b++){
        const T* qp = in + ((long)b*Ctot + cOff + c)*Pn;
        for (int p = blockIdx.y*256 + threadIdx.x; p < Pn; p += gridDim.y*256){
            float v = ldf(qp[p]);
            s += v; s2 = fmaf(v,v,s2);
        }
    }
    __shared__ float r1[256], r2[256];
    r1[threadIdx.x]=s; r2[threadIdx.x]=s2;
    __syncthreads();
    for (int k=128;k>0;k>>=1){
        if (threadIdx.x<k){ r1[threadIdx.x]+=r1[threadIdx.x+k]; r2[threadIdx.x]+=r2[threadIdx.x+k]; }
        __syncthreads();
    }
    if (threadIdx.x==0){ atomicAdd(&sums[2*c], r1[0]); atomicAdd(&sums[2*c+1], r2[0]); }
}

__global__ __launch_bounds__(256) void bnfin_k(const float* __restrict__ sums, float2* __restrict__ minv,
                                               int C, float invN)
{
    int c = blockIdx.x*256 + threadIdx.x;
    if (c < C){
        float m = sums[2*c]*invN;
        float var = sums[2*c+1]*invN - m*m;
        minv[c] = make_float2(m, 1.f/sqrtf(var + 1e-5f));
    }
}

__global__ __launch_bounds__(256) void la_post_pm_k(const short* __restrict__ y, const float2* __restrict__ minv,
                                                    short* __restrict__ xatt)
{
    int i = blockIdx.x*256 + threadIdx.x;
    int px = i & 4095, og = (i >> 12) & 7, b = i >> 15;
    s16x8 yv = *(const s16x8*)&y[((long)b*P_IMG + px)*64 + og*8];
    s16x8 ov;
    #pragma unroll
    for (int j=0;j<8;j++){
        float2 st = minv[og*8 + j];
        float v = (bits2f(yv[j]) - st.x)*st.y;
        ov[j] = bfbits(fmaxf(v, 0.f));
    }
    *(s16x8*)&xatt[((long)b*P_IMG + px)*256 + 64 + og*8] = ov;
}

// ============ MRA ============
__global__ __launch_bounds__(256) void mp3_k(const float* __restrict__ x, float* __restrict__ mp){
    int i = blockIdx.x*256 + threadIdx.x;
    int b = i >> 18, c = (i >> 12) & 63, p = i & 4095;
    int h = p >> 6, wc = p & 63;
    const float* xb = x + ((long)b*256 + 128 + c)*P_IMG;
    float m = -3.4e38f;
    #pragma unroll
    for (int dh=-1; dh<=1; dh++){
        int hh = h+dh; if ((unsigned)hh>=64u) continue;
        #pragma unroll
        for (int dw=-1; dw<=1; dw++){
            int ww = wc+dw; if ((unsigned)ww>=64u) continue;
            m = fmaxf(m, xb[hh*64+ww]);
        }
    }
    mp[i] = m;
}

__global__ __launch_bounds__(256) void blur_k(const float* __restrict__ mp, float* __restrict__ xm){
    int idx = blockIdx.x*256 + threadIdx.x;
    int oj = idx % 22; int t = idx / 22; int oi = t % 22; int bc = t / 22;
    const float* mb = mp + (long)bc * P_IMG;
    const float fw[4] = {1.f,3.f,3.f,1.f};
    float s = 0.f;
    #pragma unroll
    for (int u=0;u<4;u++){
        int r = 3*oi - 1 + u;
        r = r < 0 ? -r : (r > 63 ? 126 - r : r);
        float rs = 0.f;
        #pragma unroll
        for (int v=0; v<4; v++){
            int qq = 3*oj - 1 + v;
            qq = qq < 0 ? -qq : (qq > 63 ? 126 - qq : qq);
            rs = fmaf(fw[v], mb[r*64+qq], rs);
        }
        s = fmaf(fw[u], rs, s);
    }
    xm[idx] = s * (1.f/64.f);
}

__global__ __launch_bounds__(256) void strips_k(const float* __restrict__ xm, const float* __restrict__ wh1,
                                                const float* __restrict__ wv1, float* __restrict__ msum)
{
    int idx = blockIdx.x*256 + threadIdx.x;
    int j = idx % 22; int t = idx / 22; int i = t % 22; int bc = t / 22; int c = bc & 63;
    const float* xb = xm + (long)bc*484;
    float s = 0.f;
    #pragma unroll
    for (int u=0;u<11;u++){
        int ii = i + u - 5; if ((unsigned)ii >= 22u) continue;
        #pragma unroll
        for (int v=0;v<3;v++){
            int jj = j + v - 1; if ((unsigned)jj >= 22u) continue;
            s = fmaf(wh1[c*33 + u*3 + v], xb[ii*22+jj], s);
        }
    }
    #pragma unroll
    for (int u=0;u<3;u++){
        int ii = i + u - 1; if ((unsigned)ii >= 22u) continue;
        #pragma unroll
        for (int v=0;v<11;v++){
            int jj = j + v - 5; if ((unsigned)jj >= 22u) continue;
            s = fmaf(wv1[c*33 + u*11 + v], xb[ii*22+jj], s);
        }
    }
    msum[idx] = s;
}

__global__ __launch_bounds__(256) void shearh_k(const float* __restrict__ xm, float* __restrict__ sh){
    int idx = blockIdx.x*256 + threadIdx.x;
    int j = idx % 43; int t = idx / 43; int i = t % 22; int bc = t / 22;
    int f = i*43 + j; int r = f / 44; int q = f - 44*r;
    sh[idx] = (q < 22) ? xm[(long)bc*484 + r*22 + q] : 0.f;
}

__global__ __launch_bounds__(256) void shconvh_k(const float* __restrict__ sh, const float* __restrict__ w2,
                                                 float* __restrict__ sh2)
{
    int idx = blockIdx.x*256 + threadIdx.x;
    int j = idx % 43; int t = idx / 43; int i = t % 22; int bc = t / 22; int c = bc & 63;
    const float* sb = sh + (long)bc*946;
    float s = 0.f;
    #pragma unroll
    for (int u=0;u<11;u++){
        int ii = i + u - 5; if ((unsigned)ii >= 22u) continue;
        #pragma unroll
        for (int v=0;v<3;v++){
            int jj = j + v - 1; if ((unsigned)jj >= 43u) continue;
            s = fmaf(w2[c*33 + u*3 + v], sb[ii*43+jj], s);
        }
    }
    sh2[idx] = s;
}

__global__ __launch_bounds__(256) void shaddh_k(const float* __restrict__ sh2, float* __restrict__ msum){
    int idx = blockIdx.x*256 + threadIdx.x;
    int j = idx % 22; int t = idx / 22; int i = t % 22; int bc = t / 22;
    int f = i*44 + j; int r = f / 43; int q = f - 43*r;
    msum[idx] += sh2[(long)bc*946 + r*43 + q];
}

__global__ __launch_bounds__(256) void shearv_k(const float* __restrict__ xm, float* __restrict__ sv){
    int idx = blockIdx.x*256 + threadIdx.x;
    int j = idx % 22; int t = idx / 22; int i = t % 43; int bc = t / 43;
    int g = j*43 + i; int r = g / 44; int q = g - 44*r;
    sv[idx] = (q < 22) ? xm[(long)bc*484 + q*22 + r] : 0.f;
}

__global__ __launch_bounds__(256) void shconvv_k(const float* __restrict__ sv, const float* __restrict__ wv2,
                                                 float* __restrict__ sv2)
{
    int idx = blockIdx.x*256 + threadIdx.x;
    int j = idx % 22; int t = idx / 22; int i = t % 43; int bc = t / 43; int c = bc & 63;
    const float* sb = sv + (long)bc*946;
    float s = 0.f;
    #pragma unroll
    for (int u=0;u<3;u++){
        int ii = i + u - 1; if ((unsigned)ii >= 43u) continue;
        #pragma unroll
        for (int v=0;v<11;v++){
            int jj = j + v - 5; if ((unsigned)jj >= 22u) continue;
            s = fmaf(wv2[c*33 + u*11 + v], sb[ii*22+jj], s);
        }
    }
    sv2[idx] = s;
}

__global__ __launch_bounds__(256) void shaddv_k(const float* __restrict__ sv2, float* __restrict__ msum){
    int idx = blockIdx.x*256 + threadIdx.x;
    int xcol = idx % 22; int t = idx / 22; int y = t % 22; int bc = t / 22;
    int g = xcol*44 + y; int r = g / 43; int q = g - 43*r;
    msum[idx] += sv2[(long)bc*946 + q*22 + r];
}

__global__ __launch_bounds__(256) void mra_gate_pm_k(const float* __restrict__ x, const float* __restrict__ msum,
                                                     const float2* __restrict__ minv, short* __restrict__ xatt)
{
    int i = blockIdx.x*256 + threadIdx.x;
    int px = i & 4095, og = (i >> 12) & 7, b = i >> 15;
    int h = px >> 6, wcol = px & 63;
    int ri = (h*22) >> 6, ci = (wcol*22) >> 6;
    s16x8 ov;
    #pragma unroll
    for (int j=0;j<8;j++){
        int c = og*8 + j;
        float g = msum[((long)b*64 + c)*484 + ri*22 + ci];
        float2 st = minv[c];
        g = sigm((g - st.x)*st.y);
        float xv = x[((long)b*256 + 128 + c)*P_IMG + px];
        ov[j] = bfbits(xv * g);
    }
    *(s16x8*)&xatt[((long)b*P_IMG + px)*256 + 128 + og*8] = ov;
}

// ============ GA ============
__global__ __launch_bounds__(256) void pool1_k(const float* __restrict__ x, float* __restrict__ x4p,
                                               int* __restrict__ idx1)
{
    int i = blockIdx.x*256 + threadIdx.x;
    int b = i >> 16, c = (i >> 10) & 63, s = i & 1023;
    int y = s >> 5, xc = s & 31;
    const float* xb = x + ((long)b*256 + 192 + c)*P_IMG;
    float v00 = xb[(2*y)*64 + 2*xc];
    float v01 = xb[(2*y)*64 + 2*xc + 1];
    float v10 = xb[(2*y+1)*64 + 2*xc];
    float v11 = xb[(2*y+1)*64 + 2*xc + 1];
    float best = v00; int bi = 0;
    if (v01 > best){ best = v01; bi = 1; }
    if (v10 > best){ best = v10; bi = 2; }
    if (v11 > best){ best = v11; bi = 3; }
    x4p[i] = best; idx1[i] = bi;
}

__global__ __launch_bounds__(256) void pool2_k(const float* __restrict__ x4p, float* __restrict__ xp,
                                               int* __restrict__ idx2)
{
    int i = blockIdx.x*256 + threadIdx.x;
    int b = i >> 14, c = (i >> 8) & 63, s = i & 255;
    int y = s >> 4, xc = s & 15;
    const float* xb = x4p + ((long)b*64 + c)*1024;
    float v00 = xb[(2*y)*32 + 2*xc];
    float v01 = xb[(2*y)*32 + 2*xc + 1];
    float v10 = xb[(2*y+1)*32 + 2*xc];
    float v11 = xb[(2*y+1)*32 + 2*xc + 1];
    float best = v00; int bi = 0;
    if (v01 > best){ best = v01; bi = 1; }
    if (v10 > best){ best = v10; bi = 2; }
    if (v11 > best){ best = v11; bi = 3; }
    xp[i] = best; idx2[i] = bi;
}

__global__ __launch_bounds__(256) void ga_proj_k(const float* __restrict__ in, const float* __restrict__ mul,
                                                 const float* __restrict__ w, const float* __restrict__ bias,
                                                 float* __restrict__ out, int Cout, int relu)
{
    int s = threadIdx.x, og = blockIdx.x, b = blockIdx.y;
    float acc[8];
    #pragma unroll
    for (int j=0;j<8;j++) acc[j]=0.f;
    for (int c=0;c<64;c++){
        float v = in[((long)b*64 + c)*256 + s];
        if (mul) v *= mul[((long)b*64 + c)*256 + s];
        #pragma unroll
        for (int j=0;j<8;j++) acc[j] = fmaf(v, w[(og*8 + j)*64 + c], acc[j]);
    }
    #pragma unroll
    for (int j=0;j<8;j++){
        int o = og*8 + j;
        float val = acc[j] + bias[o];
        if (relu) val = fmaxf(val, 0.f);
        out[((long)b*Cout + o)*256 + s] = val;
    }
}

__global__ __launch_bounds__(256) void ga_dw5_k(const float* __restrict__ h, const float* __restrict__ w,
                                                const float* __restrict__ bias, float* __restrict__ a1)
{
    int i = blockIdx.x*256 + threadIdx.x;
    int b = i >> 14, c = (i >> 8) & 63, s = i & 255;
    int y = s >> 4, x = s & 15;
    const float* hb = h + ((long)b*64 + c)*256;
    float acc = bias[c];
    #pragma unroll
    for (int u=0;u<5;u++){
        int yy = y + u - 2; if ((unsigned)yy >= 16u) continue;
        #pragma unroll
        for (int v=0;v<5;v++){
            int xx = x + v - 2; if ((unsigned)xx >= 16u) continue;
            acc = fmaf(w[c*25 + u*5 + v], hb[yy*16 + xx], acc);
        }
    }
    a1[i] = acc;
}

__global__ __launch_bounds__(256) void ga_dw7_k(const float* __restrict__ a1, const float* __restrict__ w,
                                                const float* __restrict__ bias, float* __restrict__ a2)
{
    int i = blockIdx.x*256 + threadIdx.x;
    int b = i >> 14, c = (i >> 8) & 63, s = i & 255;
    int y = s >> 4, x = s & 15;
    const float* ab = a1 + ((long)b*64 + c)*256;
    float acc = bias[c];
    #pragma unroll
    for (int u=0;u<7;u++){
        int yy = y + 3*(u-3); if ((unsigned)yy >= 16u) continue;
        #pragma unroll
        for (int v=0;v<7;v++){
            int xx = x + 3*(v-3); if ((unsigned)xx >= 16u) continue;
            acc = fmaf(w[c*49 + u*7 + v], ab[yy*16 + xx], acc);
        }
    }
    a2[i] = acc;
}

__global__ __launch_bounds__(256) void ga_agg_k(const float* __restrict__ a1s, const float* __restrict__ a2s,
                                                float* __restrict__ agg)
{
    int i = blockIdx.x*256 + threadIdx.x;
    int b = i >> 8, s = i & 255;
    float sum = 0.f, mx = -3.4e38f;
    for (int c=0;c<32;c++){
        float v = a1s[((long)b*32 + c)*256 + s];
        sum += v; mx = fmaxf(mx, v);
    }
    for (int c=0;c<32;c++){
        float v = a2s[((long)b*32 + c)*256 + s];
        sum += v; mx = fmaxf(mx, v);
    }
    agg[((long)b*2 + 0)*256 + s] = sum * (1.f/64.f);
    agg[((long)b*2 + 1)*256 + s] = mx;
}

__global__ __launch_bounds__(256) void ga_sq_k(const float* __restrict__ agg, const float* __restrict__ w,
                                               const float* __restrict__ bias, float* __restrict__ sig)
{
    int i = blockIdx.x*256 + threadIdx.x;
    int b = i >> 9, o = (i >> 8) & 1, s = i & 255;
    int y = s >> 4, x = s & 15;
    float acc = bias[o];
    for (int ic=0; ic<2; ic++){
        const float* ab = agg + ((long)b*2 + ic)*256;
        #pragma unroll
        for (int u=0;u<7;u++){
            int yy = y + u - 3; if ((unsigned)yy >= 16u) continue;
            #pragma unroll
            for (int v=0;v<7;v++){
                int xx = x + v - 3; if ((unsigned)xx >= 16u) continue;
                acc = fmaf(w[((o*2 + ic)*7 + u)*7 + v], ab[yy*16 + xx], acc);
            }
        }
    }
    sig[i] = sigm(acc);
}

__global__ __launch_bounds__(256) void ga_attn_k(const float* __restrict__ a1s, const float* __restrict__ a2s,
                                                 const float* __restrict__ sig, const float* __restrict__ w,
                                                 const float* __restrict__ bias, float* __restrict__ attn)
{
    int s = threadIdx.x, og = blockIdx.x, b = blockIdx.y;
    float s0 = sig[((long)b*2 + 0)*256 + s];
    float s1 = sig[((long)b*2 + 1)*256 + s];
    float acc[8];
    #pragma unroll
    for (int j=0;j<8;j++) acc[j]=0.f;
    for (int c=0;c<32;c++){
        float v = a1s[((long)b*32 + c)*256 + s]*s0 + a2s[((long)b*32 + c)*256 + s]*s1;
        #pragma unroll
        for (int j=0;j<8;j++) acc[j] = fmaf(v, w[(og*8 + j)*32 + c], acc[j]);
    }
    #pragma unroll
    for (int j=0;j<8;j++){
        int o = og*8 + j;
        attn[((long)b*64 + o)*256 + s] = acc[j] + bias[o];
    }
}

__global__ __launch_bounds__(256) void ga_unpool1_k(const float* __restrict__ h2, const int* __restrict__ idx2,
                                                    float* __restrict__ xg)
{
    int i = blockIdx.x*256 + threadIdx.x;
    int b = i >> 16, c = (i >> 10) & 63, s = i & 1023;
    int Y = s >> 5, X = s & 31;
    int slot = ((Y & 1) << 1) | (X & 1);
    long pi = ((long)b*64 + c)*256 + (Y >> 1)*16 + (X >> 1);
    xg[i] = (idx2[pi] == slot) ? h2[pi] : 0.f;
}

__global__ __launch_bounds__(256) void ga_out_pm_k(const float* __restrict__ xg, const int* __restrict__ idx1,
                                                   const float2* __restrict__ minv, short* __restrict__ xatt)
{
    int i = blockIdx.x*256 + threadIdx.x;
    int px = i & 4095, og = (i >> 12) & 7, b = i >> 15;
    int hh = px >> 6, ww = px & 63;
    int slot = ((hh & 1) << 1) | (ww & 1);
    s16x8 ov;
    #pragma unroll
    for (int j=0;j<8;j++){
        int c = og*8 + j;
        long pi = ((long)b*64 + c)*1024 + (hh >> 1)*32 + (ww >> 1);
        float v = 0.f;
        if (idx1[pi] == slot){
            float2 st = minv[c];
            v = (xg[pi] - st.x)*st.y;
        }
        ov[j] = bfbits(v);
    }
    *(s16x8*)&xatt[((long)b*P_IMG + px)*256 + 192 + og*8] = ov;
}

// ============================================================================
extern "C" void kernel_launch(void* const* d_in, const int* in_sizes, int n_in,
                              void* d_out, int out_size, void* d_ws, size_t ws_size,
                              hipStream_t stream)
{
    const float* x      = (const float*)d_in[0];
    const float* pa_w1  = (const float*)d_in[1];
    const float* pa_w2  = (const float*)d_in[2];
    const float* la_w   = (const float*)d_in[3];
    const float* mra_h1 = (const float*)d_in[4];
    const float* mra_v1 = (const float*)d_in[5];
    const float* mra_h2 = (const float*)d_in[6];
    const float* mra_v2 = (const float*)d_in[7];
    const float* g_p1w  = (const float*)d_in[8];
    const float* g_p1b  = (const float*)d_in[9];
    const float* g_c0w  = (const float*)d_in[10];
    const float* g_c0b  = (const float*)d_in[11];
    const float* g_spw  = (const float*)d_in[12];
    const float* g_spb  = (const float*)d_in[13];
    const float* g_c1w  = (const float*)d_in[14];
    const float* g_c1b  = (const float*)d_in[15];
    const float* g_c2w  = (const float*)d_in[16];
    const float* g_c2b  = (const float*)d_in[17];
    const float* g_cw   = (const float*)d_in[18];
    const float* g_cb   = (const float*)d_in[19];
    const float* g_sqw  = (const float*)d_in[20];
    const float* g_sqb  = (const float*)d_in[21];
    const float* g_p2w  = (const float*)d_in[22];
    const float* g_p2b  = (const float*)d_in[23];
    const float* mlp_w1 = (const float*)d_in[24];
    const float* mlp_w2 = (const float*)d_in[25];
    float* outp = (float*)d_out;
    char* ws = (char*)d_ws;

    if (ws_size < (size_t)WS_NEED){
        zero_out_k<<<(out_size + 255)/256, 256, 0, stream>>>(outp, out_size);
        return;
    }

    short* xatt = (short*)(ws + XATT_OFF);   // bf16 px-major (32,4096,256)
    short* tbuf = (short*)(ws + BIG_OFF);    // bf16 px-major (32,4096,256/512)
    short* xpm  = (short*)(ws + XPM_OFF);    // bf16 px-major (32,4096,128) [transient]
    short* yla  = (short*)(ws + YLA_OFF);    // bf16 px-major (32,4096,64)  [transient]
    float* xm   = (float*)(ws + XM_OFF);
    float* msum = (float*)(ws + MSUM_OFF);
    float* sh   = (float*)(ws + SH_OFF);
    float* sh2  = (float*)(ws + SH2_OFF);
    float* x4p  = (float*)(ws + X4P_OFF);
    int*   idx1 = (int*)(ws + IDX1_OFF);
    float* xp   = (float*)(ws + XP_OFF);
    int*   idx2 = (int*)(ws + IDX2_OFF);
    float* hbuf = (float*)(ws + HBUF_OFF);
    float* a1   = (float*)(ws + A1_OFF);
    float* a2   = (float*)(ws + A2_OFF);
    float* a1s  = (float*)(ws + A1S_OFF);
    float* a2s  = (float*)(ws + A2S_OFF);
    float* agg  = (float*)(ws + AGG_OFF);
    float* sig  = (float*)(ws + SIG_OFF);
    float* attn = (float*)(ws + ATTN_OFF);
    float* h2   = (float*)(ws + H2_OFF);
    float* xg   = (float*)(ws + XG_OFF);
    float* p33  = (float*)(ws + P33_OFF);
    float* raw  = (float*)(ws + STATS_OFF);
    float*  raw_pa  = raw;
    float*  raw_la  = raw + 512;
    float*  raw_mra = raw + 640;
    float*  raw_ga  = raw + 768;
    float*  raw_mlp = raw + 896;
    float2* mv_pa   = (float2*)(raw + 1920);
    float2* mv_la   = mv_pa + 256;
    float2* mv_mra  = mv_la + 64;
    float2* mv_ga   = mv_mra + 64;
    float2* mv_mlp  = mv_ga + 64;

    hipMemsetAsync(raw, 0, 1920*sizeof(float), stream);

    // ---- packed weights (PA + LA) live in the p33 region, dead until mp3_k ----
    short* wp_pa1 = (short*)(ws + P33_OFF);          // 256*64
    short* wp_pa2 = wp_pa1 + 256*64;                 // 64*256
    short* wp_la  = wp_pa2 + 64*256;                 // 64*576
    packw_k<<<64,256,0,stream>>>(pa_w1, wp_pa1, 6, 16);
    packw_k<<<64,256,0,stream>>>(pa_w2, wp_pa2, 8, 4);
    packw_la_k<<<144,256,0,stream>>>(la_w, wp_la);

    // ---- transpose x[:,0:128] -> px-major bf16 (feeds PA expand + LA conv) ----
    xpose_pm_k<<<8192,256,0,stream>>>(x, xpm);

    // ---- PA ----
    convmfma_dma_k<<<dim3(64,4,32),256,0,stream>>>(xpm,128,0, wp_pa1,64,16, tbuf,256);
    bnstats_pm_k<256><<<dim3(16,32),256,0,stream>>>(tbuf, raw_pa);
    bnfin_k<<<1,256,0,stream>>>(raw_pa, mv_pa, 256, 1.f/131072.f);
    convmfma_reg_k<1,short><<<dim3(64,1,32),256,0,stream>>>(tbuf,256,0, mv_pa, wp_pa2,256,4,
                                                            xatt,256,0, x,256,0);

    // ---- LA (implicit-GEMM 3x3 on MFMA) ----
    la_mfma_k<<<dim3(64,1,32),256,0,stream>>>(xpm, wp_la, yla);
    bnstats_pm_k<64><<<dim3(16,32),256,0,stream>>>(yla, raw_la);
    bnfin_k<<<1,256,0,stream>>>(raw_la, mv_la, 64, 1.f/131072.f);
    la_post_pm_k<<<4096,256,0,stream>>>(yla, mv_la, xatt);

    // ---- MRA ---- (p33 reused as maxpool3 buffer; xpm/yla dead from here)
    mp3_k<<<32768,256,0,stream>>>(x, p33);
    blur_k<<<3872,256,0,stream>>>(p33, xm);
    strips_k<<<3872,256,0,stream>>>(xm, mra_h1, mra_v1, msum);
    shearh_k<<<7568,256,0,stream>>>(xm, sh);
    shconvh_k<<<7568,256,0,stream>>>(sh, mra_h2, sh2);
    shaddh_k<<<3872,256,0,stream>>>(sh2, msum);
    shearv_k<<<7568,256,0,stream>>>(xm, sh);
    shconvv_k<<<7568,256,0,stream>>>(sh, mra_v2, sh2);
    shaddv_k<<<3872,256,0,stream>>>(sh2, msum);
    bnstats_k<float><<<dim3(64,2),256,0,stream>>>(msum,64,0,484, raw_mra);
    bnfin_k<<<1,256,0,stream>>>(raw_mra, mv_mra, 64, 1.f/15488.f);
    mra_gate_pm_k<<<4096,256,0,stream>>>(x, msum, mv_mra, xatt);

    // ---- GA ----
    pool1_k<<<8192,256,0,stream>>>(x, x4p, idx1);
    pool2_k<<<2048,256,0,stream>>>(x4p, xp, idx2);
    ga_proj_k<<<dim3(8,32),256,0,stream>>>(xp, nullptr, g_p1w, g_p1b, hbuf, 64, 1);
    ga_dw5_k<<<2048,256,0,stream>>>(hbuf, g_c0w, g_c0b, a1);
    ga_dw7_k<<<2048,256,0,stream>>>(a1, g_spw, g_spb, a2);
    ga_proj_k<<<dim3(4,32),256,0,stream>>>(a1, nullptr, g_c1w, g_c1b, a1s, 32, 0);
    ga_proj_k<<<dim3(4,32),256,0,stream>>>(a2, nullptr, g_c2w, g_c2b, a2s, 32, 0);
    ga_agg_k<<<32,256,0,stream>>>(a1s, a2s, agg);
    ga_sq_k<<<64,256,0,stream>>>(agg, g_sqw, g_sqb, sig);
    ga_attn_k<<<dim3(8,32),256,0,stream>>>(a1s, a2s, sig, g_cw, g_cb, attn);
    ga_proj_k<<<dim3(8,32),256,0,stream>>>(hbuf, attn, g_p2w, g_p2b, h2, 64, 0);
    ga_unpool1_k<<<8192,256,0,stream>>>(h2, idx2, xg);
    bnstats_k<float><<<dim3(64,4),256,0,stream>>>(xg,64,0,1024, raw_ga);
    bnfin_k<<<1,256,0,stream>>>(raw_ga, mv_ga, 64, 1.f/32768.f);
    ga_out_pm_k<<<4096,256,0,stream>>>(xg, idx1, mv_ga, xatt);

    // ---- MLP residual ---- (p33 region dead again -> pack MLP weights there)
    short* wm1 = (short*)(ws + P33_OFF);             // 512*256
    short* wm2 = wm1 + 512*256;                      // 256*512
    packw_k<<<512,256,0,stream>>>(mlp_w1, wm1, 8, 32);
    packw_k<<<512,256,0,stream>>>(mlp_w2, wm2, 9, 16);
    convmfma_dma_k<<<dim3(64,8,32),256,0,stream>>>(xatt,256,0, wm1,256,32, tbuf,512);
    bnstats_pm_k<512><<<dim3(16,32),256,0,stream>>>(tbuf, raw_mlp);
    bnfin_k<<<2,256,0,stream>>>(raw_mlp, mv_mlp, 512, 1.f/131072.f);
    convmfma_reg_k<2,float><<<dim3(64,4,32),256,0,stream>>>(tbuf,512,0, mv_mlp, wm2,512,16,
                                                            outp,256,0, x,256,0);
}

// Round 3
// 980.707 us; speedup vs baseline: 2.0038x; 1.0691x over previous
//
#include <hip/hip_runtime.h>
#include <hip/hip_bf16.h>
#include <math.h>

typedef __hip_bfloat16 bf16;
typedef __attribute__((ext_vector_type(4))) float f32x4;
typedef __attribute__((ext_vector_type(8))) short s16x8;
typedef __attribute__((ext_vector_type(4))) short s16x4;

static __device__ __forceinline__ float bits2f(short s){ return __uint_as_float(((unsigned)(unsigned short)s)<<16); }
static __device__ __forceinline__ short bfbits(float f){ bf16 h = __float2bfloat16(f); return *reinterpret_cast<short*>(&h); }
static __device__ __forceinline__ float ldf(float v){ return v; }
static __device__ __forceinline__ float sigm(float v){ return 1.f/(1.f+__expf(-v)); }

#define P_IMG 4096   // 64*64

#define GLDS16(SRC, DST) __builtin_amdgcn_global_load_lds( \
    (__attribute__((address_space(1))) void*)(SRC), \
    (__attribute__((address_space(3))) void*)(DST), 16, 0, 0)

// ---------------- workspace layout (bytes) ----------------
namespace {
constexpr long long XATT_OFF = 0;            // bf16 px-major (32,4096,256) = 64MB
constexpr long long BIG_OFF  = 67108864;     // tbuf: bf16 px-major (32,4096,256) or (32,4096,512)
constexpr long long MISC     = 134217728;
constexpr long long XM_OFF   = MISC;                 // f32 (2048,484)
constexpr long long MSUM_OFF = MISC + 3964928;       // f32 (2048,484)
constexpr long long SH_OFF   = MISC + 7929856;       // (unused now)
constexpr long long SH2_OFF  = MISC + 15679488;      // (unused now)
constexpr long long X4P_OFF  = MISC + 23429120;      // f32 (32,64,1024)
constexpr long long IDX1_OFF = MISC + 31817728;      // i32 (32,64,1024)
constexpr long long XP_OFF   = MISC + 40206336;      // f32 (32,64,256)
constexpr long long IDX2_OFF = MISC + 42303488;      // i32
constexpr long long HBUF_OFF = MISC + 44400640;      // f32 (32,64,256)
constexpr long long A1_OFF   = MISC + 46497792;
constexpr long long A2_OFF   = MISC + 48594944;
constexpr long long A1S_OFF  = MISC + 50692096;      // f32 (32,32,256)
constexpr long long A2S_OFF  = MISC + 51740672;
constexpr long long AGG_OFF  = MISC + 52789248;      // f32 (32,2,256)
constexpr long long SIG_OFF  = MISC + 52854784;
constexpr long long ATTN_OFF = MISC + 52920320;      // f32 (32,64,256)
constexpr long long H2_OFF   = MISC + 55017472;
constexpr long long XG_OFF   = MISC + 57114624;      // f32 (32,64,1024)
constexpr long long P33_OFF  = 201326592;            // f32 (32,64,4096); also hosts packed weights
constexpr long long STATS_OFF= 234881024;
constexpr long long WS_NEED  = 234897408;
// transient (PA/LA phase only, dead once MRA starts): xpm + y_la live in MISC region
constexpr long long XPM_OFF  = MISC;                 // bf16 (32,4096,128) = 32MB
constexpr long long YLA_OFF  = MISC + 33554432;      // bf16 (32,4096,64) = 16MB
}

__global__ __launch_bounds__(256) void zero_out_k(float* __restrict__ o, int n){
    int i = blockIdx.x*256 + threadIdx.x;
    if (i < n) o[i] = 0.f;
}

// ======== weight pre-pack: f32 [O][K] -> bf16 fragment-major ========
// frag layout: idx = ((((k>>6)*2 + kk)*OT16 + (o>>4))*4 + q)*16 + m16)*8 + r
__global__ __launch_bounds__(256) void packw_k(const float* __restrict__ W, short* __restrict__ Wp,
                                               int kshift, int OT16)
{
    int i = blockIdx.x*256 + threadIdx.x;
    int o = i >> kshift;
    int k = i & ((1<<kshift)-1);
    long dest = (((((long)(k>>6)*2 + ((k>>5)&1))*OT16 + (o>>4))*4 + ((k>>3)&3))*16 + (o&15))*8 + (k&7);
    Wp[dest] = bfbits(W[i]);
}

// LA weights (64,64,9) o,c,tap -> packed with k = tap*64 + c, K=576, OT16=4
__global__ __launch_bounds__(256) void packw_la_k(const float* __restrict__ W, short* __restrict__ Wp)
{
    int i = blockIdx.x*256 + threadIdx.x;   // 64*576 = 36864
    int o = i / 576, k = i - o*576;
    int tap = k >> 6, c = k & 63;
    long dest = (((((long)(k>>6)*2 + ((k>>5)&1))*4 + (o>>4))*4 + ((k>>3)&3))*16 + (o&15))*8 + (k&7);
    Wp[dest] = bfbits(W[(o*64 + c)*9 + tap]);
}

// ======== transpose x[b][0..128][px] f32 -> xpm[b][px][128] bf16 ========
__global__ __launch_bounds__(256) void xpose_pm_k(const float* __restrict__ x, short* __restrict__ xpm)
{
    int i = blockIdx.x*256 + threadIdx.x;   // 32*16*4096
    int px = i & 4095, og = (i >> 12) & 15, b = i >> 16;
    s16x8 ov;
    #pragma unroll
    for (int j=0;j<8;j++)
        ov[j] = bfbits(x[((long)b*256 + og*8 + j)*P_IMG + px]);
    *(s16x8*)&xpm[((long)b*P_IMG + px)*128 + og*8] = ov;
}

// ======== generic 1x1 MFMA conv, px-major bf16 in, global_load_lds staging ========
// block = 64 px  x  (32*MT) out-ch
template<int MT>
__global__ __launch_bounds__(256) void convmfma_dma_k(
    const short* __restrict__ in, int inCtot, int inOff,
    const short* __restrict__ Wp, int K, int OT16,
    short* __restrict__ out, int outC)
{
    __shared__ __align__(16) short sB[64*64];
    const int tid = threadIdx.x;
    const int b = blockIdx.z;
    const int Mbase = blockIdx.y * (32*MT);
    const int pxBase = blockIdx.x * 64;
    const int lane = tid & 63, w = tid >> 6;
    const int n16 = lane & 15, q = lane >> 4;
    const int wm = w >> 1, wn = w & 1;
    const int otBase = (Mbase>>4) + wm*MT;

    f32x4 zero = {0.f,0.f,0.f,0.f};
    f32x4 acc[MT][2];
    #pragma unroll
    for (int mt=0;mt<MT;mt++){ acc[mt][0]=zero; acc[mt][1]=zero; }

    const int drow_lo = lane >> 3;
    const int chunk = lane & 7;

    for (int kb = 0; kb < K; kb += 64){
        __syncthreads();
        #pragma unroll
        for (int s = 0; s < 2; s++){
            int seg = w*2 + s;
            int row = seg*8 + drow_lo;
            int kg = chunk ^ (row & 7);
            const short* src = in + ((long)b*P_IMG + pxBase + row)*inCtot + inOff + kb + kg*8;
            GLDS16(src, (char*)sB + seg*1024);
        }
        __syncthreads();
        #pragma unroll
        for (int kk = 0; kk < 2; kk++){
            s16x8 afr[MT], bfr[2];
            #pragma unroll
            for (int mt=0; mt<MT; mt++)
                afr[mt] = *(const s16x8*)(Wp + ((((long)(kb>>6)*2 + kk)*OT16 + otBase + mt)*64 + lane)*8);
            #pragma unroll
            for (int nt=0; nt<2; nt++){
                int n = wn*32 + nt*16 + n16;
                int g = (kk*4 + q) ^ (n & 7);
                bfr[nt] = *(const s16x8*)&sB[n*64 + (g<<3)];
            }
            #pragma unroll
            for (int mt=0; mt<MT; mt++)
                #pragma unroll
                for (int nt=0; nt<2; nt++)
                    acc[mt][nt] = __builtin_amdgcn_mfma_f32_16x16x32_bf16(afr[mt], bfr[nt], acc[mt][nt], 0, 0, 0);
        }
    }

    #pragma unroll
    for (int mt=0; mt<MT; mt++){
        #pragma unroll
        for (int nt=0; nt<2; nt++){
            int px = pxBase + wn*32 + nt*16 + n16;
            int o0 = Mbase + wm*(MT*16) + mt*16 + q*4;
            s16x4 ov;
            #pragma unroll
            for (int r=0; r<4; r++) ov[r] = bfbits(acc[mt][nt][r]);
            *(s16x4*)&out[((long)b*P_IMG + px)*outC + o0] = ov;
        }
    }
}

// ======== LA 3x3 conv as implicit GEMM: K = 9 taps x 64 ch ========
__global__ __launch_bounds__(256) void la_mfma_k(
    const short* __restrict__ xpm,   // [b][4096][128], LA slice at +64
    const short* __restrict__ Wp,    // packed K=576, OT16=4
    short* __restrict__ y)           // [b][4096][64] bf16
{
    __shared__ __align__(16) short sB[64*64];
    const int tid = threadIdx.x;
    const int b = blockIdx.z;
    const int hRow = blockIdx.x;
    const int pxBase = hRow*64;
    const int lane = tid & 63, w = tid >> 6;
    const int n16 = lane & 15, q = lane >> 4;
    const int wm = w >> 1, wn = w & 1;
    const int otBase = wm*2;

    f32x4 zero = {0.f,0.f,0.f,0.f};
    f32x4 acc[2][2];
    acc[0][0]=zero; acc[0][1]=zero; acc[1][0]=zero; acc[1][1]=zero;

    const int srow = tid >> 3, schunk = tid & 7;

    for (int tap = 0; tap < 9; tap++){
        const int hh = hRow + (tap/3) - 1;
        const int dw = (tap%3) - 1;
        const bool hok = (unsigned)hh < 64u;
        s16x8 stg[2];
        #pragma unroll
        for (int it = 0; it < 2; it++){
            int row = it*32 + srow;          // = wc within the row-tile
            int ww = row + dw;
            int kg = schunk ^ (row & 7);
            s16x8 v = {0,0,0,0,0,0,0,0};
            if (hok && (unsigned)ww < 64u)
                v = *(const s16x8*)(xpm + ((long)b*P_IMG + hh*64 + ww)*128 + 64 + kg*8);
            stg[it] = v;
        }
        __syncthreads();
        *(s16x8*)&sB[srow*64 + schunk*8]      = stg[0];
        *(s16x8*)&sB[(32+srow)*64 + schunk*8] = stg[1];
        __syncthreads();
        #pragma unroll
        for (int kk = 0; kk < 2; kk++){
            s16x8 afr[2], bfr[2];
            #pragma unroll
            for (int mt=0; mt<2; mt++)
                afr[mt] = *(const s16x8*)(Wp + ((((long)tap*2 + kk)*4 + otBase + mt)*64 + lane)*8);
            #pragma unroll
            for (int nt=0; nt<2; nt++){
                int n = wn*32 + nt*16 + n16;
                int g = (kk*4 + q) ^ (n & 7);
                bfr[nt] = *(const s16x8*)&sB[n*64 + (g<<3)];
            }
            #pragma unroll
            for (int mt=0; mt<2; mt++)
                #pragma unroll
                for (int nt=0; nt<2; nt++)
                    acc[mt][nt] = __builtin_amdgcn_mfma_f32_16x16x32_bf16(afr[mt], bfr[nt], acc[mt][nt], 0, 0, 0);
        }
    }

    #pragma unroll
    for (int mt=0; mt<2; mt++){
        #pragma unroll
        for (int nt=0; nt<2; nt++){
            int px = pxBase + wn*32 + nt*16 + n16;
            int o0 = wm*32 + mt*16 + q*4;
            s16x4 ov;
            #pragma unroll
            for (int r=0; r<4; r++) ov[r] = bfbits(acc[mt][nt][r]);
            *(s16x4*)&y[((long)b*P_IMG + px)*64 + o0] = ov;
        }
    }
}

// ======== BN+ReLU convs (PA gate epi=1, MLP2 epi=2): px-major bf16 in, reg staging ========
template<int EPI, typename TOUT, int MT>
__global__ __launch_bounds__(256) void convmfma_reg_k(
    const short* __restrict__ in, int inCtot, int inOff,
    const float2* __restrict__ stats,
    const short* __restrict__ Wp, int K, int OT16,
    TOUT* __restrict__ out, int outC, int outOff,
    const float* __restrict__ aux, int auxC, int auxOff)
{
    __shared__ __align__(16) short sB[64*64];
    const int tid = threadIdx.x;
    const int b = blockIdx.z;
    const int Mbase = blockIdx.y * (32*MT);
    const int pxBase = blockIdx.x * 64;
    const int lane = tid & 63, w = tid >> 6;
    const int n16 = lane & 15, q = lane >> 4;
    const int wm = w >> 1, wn = w & 1;
    const int otBase = (Mbase>>4) + wm*MT;

    f32x4 zero = {0.f,0.f,0.f,0.f};
    f32x4 acc[MT][2];
    #pragma unroll
    for (int mt=0;mt<MT;mt++){ acc[mt][0]=zero; acc[mt][1]=zero; }

    const int srow = tid >> 3, schunk = tid & 7;
    const int skg = schunk ^ (srow & 7);

    for (int kb = 0; kb < K; kb += 64){
        const f32x4* sp = (const f32x4*)(stats + kb + skg*8);
        f32x4 p0 = sp[0], p1 = sp[1], p2 = sp[2], p3 = sp[3];
        float mm[8] = {p0[0],p0[2],p1[0],p1[2],p2[0],p2[2],p3[0],p3[2]};
        float iv[8] = {p0[1],p0[3],p1[1],p1[3],p2[1],p2[3],p3[1],p3[3]};
        s16x8 stg[2];
        #pragma unroll
        for (int it = 0; it < 2; it++){
            int row = it*32 + srow;
            s16x8 rv = *(const s16x8*)(in + ((long)b*P_IMG + pxBase + row)*inCtot + inOff + kb + skg*8);
            s16x8 ov;
            #pragma unroll
            for (int j=0;j<8;j++){
                float f = bits2f(rv[j]);
                f = (f - mm[j])*iv[j];
                f = fmaxf(f, 0.f);
                ov[j] = bfbits(f);
            }
            stg[it] = ov;
        }
        __syncthreads();
        *(s16x8*)&sB[srow*64 + schunk*8]      = stg[0];
        *(s16x8*)&sB[(32+srow)*64 + schunk*8] = stg[1];
        __syncthreads();
        #pragma unroll
        for (int kk = 0; kk < 2; kk++){
            s16x8 afr[MT], bfr[2];
            #pragma unroll
            for (int mt=0; mt<MT; mt++)
                afr[mt] = *(const s16x8*)(Wp + ((((long)(kb>>6)*2 + kk)*OT16 + otBase + mt)*64 + lane)*8);
            #pragma unroll
            for (int nt=0; nt<2; nt++){
                int n = wn*32 + nt*16 + n16;
                int g = (kk*4 + q) ^ (n & 7);
                bfr[nt] = *(const s16x8*)&sB[n*64 + (g<<3)];
            }
            #pragma unroll
            for (int mt=0; mt<MT; mt++)
                #pragma unroll
                for (int nt=0; nt<2; nt++)
                    acc[mt][nt] = __builtin_amdgcn_mfma_f32_16x16x32_bf16(afr[mt], bfr[nt], acc[mt][nt], 0, 0, 0);
        }
    }

    #pragma unroll
    for (int mt=0; mt<MT; mt++){
        #pragma unroll
        for (int nt=0; nt<2; nt++){
            int px = pxBase + wn*32 + nt*16 + n16;
            int o0 = Mbase + wm*(MT*16) + mt*16 + q*4;
            if constexpr (EPI == 1){
                s16x4 ov;
                #pragma unroll
                for (int r=0; r<4; r++){
                    float av = aux[((long)b*auxC + auxOff + o0 + r)*P_IMG + px];
                    ov[r] = bfbits(av * sigm(acc[mt][nt][r]));
                }
                *(s16x4*)&(((short*)out)[((long)b*P_IMG + px)*outC + outOff + o0]) = ov;
            } else {
                #pragma unroll
                for (int r=0; r<4; r++){
                    int o = o0 + r;
                    float av = aux[((long)b*auxC + auxOff + o)*P_IMG + px];
                    out[((long)b*outC + outOff + o)*P_IMG + px] = av + acc[mt][nt][r];
                }
            }
        }
    }
}

// ============ BN batch-stats: px-major bf16 [b][4096][C] ============
template<int C>
__global__ __launch_bounds__(256) void bnstats_pm_k(const short* __restrict__ in, float* __restrict__ sums)
{
    constexpr int CH8 = C/8;
    constexpr int PL  = 256/CH8;
    __shared__ float accs[2*C];
    const int t = threadIdx.x;
    for (int i=t;i<2*C;i+=256) accs[i]=0.f;
    __syncthreads();
    const int chunk = t & (CH8-1), pl = t / CH8;
    const int b = blockIdx.y;
    float s[8], s2[8];
    #pragma unroll
    for (int j=0;j<8;j++){ s[j]=0.f; s2[j]=0.f; }
    for (int px = blockIdx.x*256 + pl; px < (blockIdx.x+1)*256; px += PL){
        s16x8 v = *(const s16x8*)&in[((long)b*P_IMG + px)*C + chunk*8];
        #pragma unroll
        for (int j=0;j<8;j++){
            float f = bits2f(v[j]);
            s[j] += f; s2[j] = fmaf(f,f,s2[j]);
        }
    }
    #pragma unroll
    for (int j=0;j<8;j++){
        atomicAdd(&accs[(chunk*8+j)*2],   s[j]);
        atomicAdd(&accs[(chunk*8+j)*2+1], s2[j]);
    }
    __syncthreads();
    for (int i=t;i<2*C;i+=256) atomicAdd(&sums[i], accs[i]);
}

// ============ BN batch-stats: c-major f32 (msum, xg) ============
template<typename T>
__global__ __launch_bounds__(256) void bnstats_k(const T* __restrict__ in, int Ctot, int cOff, int Pn,
                                                 float* __restrict__ sums)
{
    const int c = blockIdx.x;
    float s=0.f, s2=0.f;
    for (int b=0;b<32;b++){
        const T* qp = in + ((long)b*Ctot + cOff + c)*Pn;
        for (int p = blockIdx.y*256 + threadIdx.x; p < Pn; p += gridDim.y*256){
            float v = ldf(qp[p]);
            s += v; s2 = fmaf(v,v,s2);
        }
    }
    __shared__ float r1[256], r2[256];
    r1[threadIdx.x]=s; r2[threadIdx.x]=s2;
    __syncthreads();
    for (int k=128;k>0;k>>=1){
        if (threadIdx.x<k){ r1[threadIdx.x]+=r1[threadIdx.x+k]; r2[threadIdx.x]+=r2[threadIdx.x+k]; }
        __syncthreads();
    }
    if (threadIdx.x==0){ atomicAdd(&sums[2*c], r1[0]); atomicAdd(&sums[2*c+1], r2[0]); }
}

__global__ __launch_bounds__(256) void bnfin_k(const float* __restrict__ sums, float2* __restrict__ minv,
                                               int C, float invN)
{
    int c = blockIdx.x*256 + threadIdx.x;
    if (c < C){
        float m = sums[2*c]*invN;
        float var = sums[2*c+1]*invN - m*m;
        minv[c] = make_float2(m, 1.f/sqrtf(var + 1e-5f));
    }
}

__global__ __launch_bounds__(256) void la_post_pm_k(const short* __restrict__ y, const float2* __restrict__ minv,
                                                    short* __restrict__ xatt)
{
    int i = blockIdx.x*256 + threadIdx.x;
    int px = i & 4095, og = (i >> 12) & 7, b = i >> 15;
    s16x8 yv = *(const s16x8*)&y[((long)b*P_IMG + px)*64 + og*8];
    s16x8 ov;
    #pragma unroll
    for (int j=0;j<8;j++){
        float2 st = minv[og*8 + j];
        float v = (bits2f(yv[j]) - st.x)*st.y;
        ov[j] = bfbits(fmaxf(v, 0.f));
    }
    *(s16x8*)&xatt[((long)b*P_IMG + px)*256 + 64 + og*8] = ov;
}

// ============ MRA ============
__global__ __launch_bounds__(256) void mp3_k(const float* __restrict__ x, float* __restrict__ mp){
    int i = blockIdx.x*256 + threadIdx.x;
    int b = i >> 18, c = (i >> 12) & 63, p = i & 4095;
    int h = p >> 6, wc = p & 63;
    const float* xb = x + ((long)b*256 + 128 + c)*P_IMG;
    float m = -3.4e38f;
    #pragma unroll
    for (int dh=-1; dh<=1; dh++){
        int hh = h+dh; if ((unsigned)hh>=64u) continue;
        #pragma unroll
        for (int dw=-1; dw<=1; dw++){
            int ww = wc+dw; if ((unsigned)ww>=64u) continue;
            m = fmaxf(m, xb[hh*64+ww]);
        }
    }
    mp[i] = m;
}

__global__ __launch_bounds__(256) void blur_k(const float* __restrict__ mp, float* __restrict__ xm){
    int idx = blockIdx.x*256 + threadIdx.x;
    int oj = idx % 22; int t = idx / 22; int oi = t % 22; int bc = t / 22;
    const float* mb = mp + (long)bc * P_IMG;
    const float fw[4] = {1.f,3.f,3.f,1.f};
    float s = 0.f;
    #pragma unroll
    for (int u=0;u<4;u++){
        int r = 3*oi - 1 + u;
        r = r < 0 ? -r : (r > 63 ? 126 - r : r);
        float rs = 0.f;
        #pragma unroll
        for (int v=0; v<4; v++){
            int qq = 3*oj - 1 + v;
            qq = qq < 0 ? -qq : (qq > 63 ? 126 - qq : qq);
            rs = fmaf(fw[v], mb[r*64+qq], rs);
        }
        s = fmaf(fw[u], rs, s);
    }
    xm[idx] = s * (1.f/64.f);
}

// ==== fused MRA conv: strips (h1,v1) + sheared strips (h2,v2), all from xm ====
__global__ __launch_bounds__(256) void mra_conv_k(const float* __restrict__ xm,
                                                  const float* __restrict__ wh1, const float* __restrict__ wv1,
                                                  const float* __restrict__ wh2, const float* __restrict__ wv2,
                                                  float* __restrict__ msum)
{
    int idx = blockIdx.x*256 + threadIdx.x;   // 2048*484
    int j = idx % 22; int t = idx / 22; int i = t % 22; int bc = t / 22; int c = bc & 63;
    const float* xb = xm + (long)bc*484;
    float s = 0.f;
    // h1 strip 11x3
    #pragma unroll
    for (int u=0;u<11;u++){
        int ii = i + u - 5; if ((unsigned)ii >= 22u) continue;
        #pragma unroll
        for (int v=0;v<3;v++){
            int jj = j + v - 1; if ((unsigned)jj >= 22u) continue;
            s = fmaf(wh1[c*33 + u*3 + v], xb[ii*22+jj], s);
        }
    }
    // v1 strip 3x11
    #pragma unroll
    for (int u=0;u<3;u++){
        int ii = i + u - 1; if ((unsigned)ii >= 22u) continue;
        #pragma unroll
        for (int v=0;v<11;v++){
            int jj = j + v - 5; if ((unsigned)jj >= 22u) continue;
            s = fmaf(wv1[c*33 + u*11 + v], xb[ii*22+jj], s);
        }
    }
    // h2 sheared strip: msum(i,j) += sh2(r,q); sh2 = conv11x3(sh); sh = h_tf(xm)
    {
        int f = i*44 + j; int r = f/43; int q = f - 43*r;
        #pragma unroll
        for (int u=0;u<11;u++){
            int a = r + u - 5; if ((unsigned)a >= 22u) continue;
            #pragma unroll
            for (int v=0;v<3;v++){
                int bcol = q + v - 1; if ((unsigned)bcol >= 43u) continue;
                int g = a*43 + bcol; int rr = g/44; int qq = g - 44*rr;
                if (qq < 22) s = fmaf(wh2[c*33 + u*3 + v], xb[rr*22+qq], s);
            }
        }
    }
    // v2 sheared strip: msum(i,j) += sv2(q,r) with g=j*44+i; sv2 = conv3x11(sv); sv = v_tf(xm)
    {
        int g = j*44 + i; int r = g/43; int q = g - 43*r;
        #pragma unroll
        for (int u=0;u<3;u++){
            int a = q + u - 1; if ((unsigned)a >= 43u) continue;
            #pragma unroll
            for (int v=0;v<11;v++){
                int bcol = r + v - 5; if ((unsigned)bcol >= 22u) continue;
                int g2 = bcol*43 + a; int rr = g2/44; int qq = g2 - 44*rr;
                if (qq < 22) s = fmaf(wv2[c*33 + u*11 + v], xb[qq*22+rr], s);
            }
        }
    }
    msum[idx] = s;
}

__global__ __launch_bounds__(256) void mra_gate_pm_k(const float* __restrict__ x, const float* __restrict__ msum,
                                                     const float2* __restrict__ minv, short* __restrict__ xatt)
{
    int i = blockIdx.x*256 + threadIdx.x;
    int px = i & 4095, og = (i >> 12) & 7, b = i >> 15;
    int h = px >> 6, wcol = px & 63;
    int ri = (h*22) >> 6, ci = (wcol*22) >> 6;
    s16x8 ov;
    #pragma unroll
    for (int j=0;j<8;j++){
        int c = og*8 + j;
        float g = msum[((long)b*64 + c)*484 + ri*22 + ci];
        float2 st = minv[c];
        g = sigm((g - st.x)*st.y);
        float xv = x[((long)b*256 + 128 + c)*P_IMG + px];
        ov[j] = bfbits(xv * g);
    }
    *(s16x8*)&xatt[((long)b*P_IMG + px)*256 + 128 + og*8] = ov;
}

// ============ GA ============
__global__ __launch_bounds__(256) void pool1_k(const float* __restrict__ x, float* __restrict__ x4p,
                                               int* __restrict__ idx1)
{
    int i = blockIdx.x*256 + threadIdx.x;
    int b = i >> 16, c = (i >> 10) & 63, s = i & 1023;
    int y = s >> 5, xc = s & 31;
    const float* xb = x + ((long)b*256 + 192 + c)*P_IMG;
    float v00 = xb[(2*y)*64 + 2*xc];
    float v01 = xb[(2*y)*64 + 2*xc + 1];
    float v10 = xb[(2*y+1)*64 + 2*xc];
    float v11 = xb[(2*y+1)*64 + 2*xc + 1];
    float best = v00; int bi = 0;
    if (v01 > best){ best = v01; bi = 1; }
    if (v10 > best){ best = v10; bi = 2; }
    if (v11 > best){ best = v11; bi = 3; }
    x4p[i] = best; idx1[i] = bi;
}

__global__ __launch_bounds__(256) void pool2_k(const float* __restrict__ x4p, float* __restrict__ xp,
                                               int* __restrict__ idx2)
{
    int i = blockIdx.x*256 + threadIdx.x;
    int b = i >> 14, c = (i >> 8) & 63, s = i & 255;
    int y = s >> 4, xc = s & 15;
    const float* xb = x4p + ((long)b*64 + c)*1024;
    float v00 = xb[(2*y)*32 + 2*xc];
    float v01 = xb[(2*y)*32 + 2*xc + 1];
    float v10 = xb[(2*y+1)*32 + 2*xc];
    float v11 = xb[(2*y+1)*32 + 2*xc + 1];
    float best = v00; int bi = 0;
    if (v01 > best){ best = v01; bi = 1; }
    if (v10 > best){ best = v10; bi = 2; }
    if (v11 > best){ best = v11; bi = 3; }
    xp[i] = best; idx2[i] = bi;
}

__global__ __launch_bounds__(256) void ga_proj_k(const float* __restrict__ in, const float* __restrict__ mul,
                                                 const float* __restrict__ w, const float* __restrict__ bias,
                                                 float* __restrict__ out, int Cout, int relu)
{
    int s = threadIdx.x, og = blockIdx.x, b = blockIdx.y;
    float acc[8];
    #pragma unroll
    for (int j=0;j<8;j++) acc[j]=0.f;
    for (int c=0;c<64;c++){
        float v = in[((long)b*64 + c)*256 + s];
        if (mul) v *= mul[((long)b*64 + c)*256 + s];
        #pragma unroll
        for (int j=0;j<8;j++) acc[j] = fmaf(v, w[(og*8 + j)*64 + c], acc[j]);
    }
    #pragma unroll
    for (int j=0;j<8;j++){
        int o = og*8 + j;
        float val = acc[j] + bias[o];
        if (relu) val = fmaxf(val, 0.f);
        out[((long)b*Cout + o)*256 + s] = val;
    }
}

__global__ __launch_bounds__(256) void ga_dw5_k(const float* __restrict__ h, const float* __restrict__ w,
                                                const float* __restrict__ bias, float* __restrict__ a1)
{
    int i = blockIdx.x*256 + threadIdx.x;
    int b = i >> 14, c = (i >> 8) & 63, s = i & 255;
    int y = s >> 4, x = s & 15;
    const float* hb = h + ((long)b*64 + c)*256;
    float acc = bias[c];
    #pragma unroll
    for (int u=0;u<5;u++){
        int yy = y + u - 2; if ((unsigned)yy >= 16u) continue;
        #pragma unroll
        for (int v=0;v<5;v++){
            int xx = x + v - 2; if ((unsigned)xx >= 16u) continue;
            acc = fmaf(w[c*25 + u*5 + v], hb[yy*16 + xx], acc);
        }
    }
    a1[i] = acc;
}

__global__ __launch_bounds__(256) void ga_dw7_k(const float* __restrict__ a1, const float* __restrict__ w,
                                                const float* __restrict__ bias, float* __restrict__ a2)
{
    int i = blockIdx.x*256 + threadIdx.x;
    int b = i >> 14, c = (i >> 8) & 63, s = i & 255;
    int y = s >> 4, x = s & 15;
    const float* ab = a1 + ((long)b*64 + c)*256;
    float acc = bias[c];
    #pragma unroll
    for (int u=0;u<7;u++){
        int yy = y + 3*(u-3); if ((unsigned)yy >= 16u) continue;
        #pragma unroll
        for (int v=0;v<7;v++){
            int xx = x + 3*(v-3); if ((unsigned)xx >= 16u) continue;
            acc = fmaf(w[c*49 + u*7 + v], ab[yy*16 + xx], acc);
        }
    }
    a2[i] = acc;
}

__global__ __launch_bounds__(256) void ga_agg_k(const float* __restrict__ a1s, const float* __restrict__ a2s,
                                                float* __restrict__ agg)
{
    int i = blockIdx.x*256 + threadIdx.x;
    int b = i >> 8, s = i & 255;
    float sum = 0.f, mx = -3.4e38f;
    for (int c=0;c<32;c++){
        float v = a1s[((long)b*32 + c)*256 + s];
        sum += v; mx = fmaxf(mx, v);
    }
    for (int c=0;c<32;c++){
        float v = a2s[((long)b*32 + c)*256 + s];
        sum += v; mx = fmaxf(mx, v);
    }
    agg[((long)b*2 + 0)*256 + s] = sum * (1.f/64.f);
    agg[((long)b*2 + 1)*256 + s] = mx;
}

__global__ __launch_bounds__(256) void ga_sq_k(const float* __restrict__ agg, const float* __restrict__ w,
                                               const float* __restrict__ bias, float* __restrict__ sig)
{
    int i = blockIdx.x*256 + threadIdx.x;
    int b = i >> 9, o = (i >> 8) & 1, s = i & 255;
    int y = s >> 4, x = s & 15;
    float acc = bias[o];
    for (int ic=0; ic<2; ic++){
        const float* ab = agg + ((long)b*2 + ic)*256;
        #pragma unroll
        for (int u=0;u<7;u++){
            int yy = y + u - 3; if ((unsigned)yy >= 16u) continue;
            #pragma unroll
            for (int v=0;v<7;v++){
                int xx = x + v - 3; if ((unsigned)xx >= 16u) continue;
                acc = fmaf(w[((o*2 + ic)*7 + u)*7 + v], ab[yy*16 + xx], acc);
            }
        }
    }
    sig[i] = sigm(acc);
}

__global__ __launch_bounds__(256) void ga_attn_k(const float* __restrict__ a1s, const float* __restrict__ a2s,
                                                 const float* __restrict__ sig, const float* __restrict__ w,
                                                 const float* __restrict__ bias, float* __restrict__ attn)
{
    int s = threadIdx.x, og = blockIdx.x, b = blockIdx.y;
    float s0 = sig[((long)b*2 + 0)*256 + s];
    float s1 = sig[((long)b*2 + 1)*256 + s];
    float acc[8];
    #pragma unroll
    for (int j=0;j<8;j++) acc[j]=0.f;
    for (int c=0;c<32;c++){
        float v = a1s[((long)b*32 + c)*256 + s]*s0 + a2s[((long)b*32 + c)*256 + s]*s1;
        #pragma unroll
        for (int j=0;j<8;j++) acc[j] = fmaf(v, w[(og*8 + j)*32 + c], acc[j]);
    }
    #pragma unroll
    for (int j=0;j<8;j++){
        int o = og*8 + j;
        attn[((long)b*64 + o)*256 + s] = acc[j] + bias[o];
    }
}

__global__ __launch_bounds__(256) void ga_unpool1_k(const float* __restrict__ h2, const int* __restrict__ idx2,
                                                    float* __restrict__ xg)
{
    int i = blockIdx.x*256 + threadIdx.x;
    int b = i >> 16, c = (i >> 10) & 63, s = i & 1023;
    int Y = s >> 5, X = s & 31;
    int slot = ((Y & 1) << 1) | (X & 1);
    long pi = ((long)b*64 + c)*256 + (Y >> 1)*16 + (X >> 1);
    xg[i] = (idx2[pi] == slot) ? h2[pi] : 0.f;
}

__global__ __launch_bounds__(256) void ga_out_pm_k(const float* __restrict__ xg, const int* __restrict__ idx1,
                                                   const float2* __restrict__ minv, short* __restrict__ xatt)
{
    int i = blockIdx.x*256 + threadIdx.x;
    int px = i & 4095, og = (i >> 12) & 7, b = i >> 15;
    int hh = px >> 6, ww = px & 63;
    int slot = ((hh & 1) << 1) | (ww & 1);
    s16x8 ov;
    #pragma unroll
    for (int j=0;j<8;j++){
        int c = og*8 + j;
        long pi = ((long)b*64 + c)*1024 + (hh >> 1)*32 + (ww >> 1);
        float v = 0.f;
        if (idx1[pi] == slot){
            float2 st = minv[c];
            v = (xg[pi] - st.x)*st.y;
        }
        ov[j] = bfbits(v);
    }
    *(s16x8*)&xatt[((long)b*P_IMG + px)*256 + 192 + og*8] = ov;
}

// ============================================================================
extern "C" void kernel_launch(void* const* d_in, const int* in_sizes, int n_in,
                              void* d_out, int out_size, void* d_ws, size_t ws_size,
                              hipStream_t stream)
{
    const float* x      = (const float*)d_in[0];
    const float* pa_w1  = (const float*)d_in[1];
    const float* pa_w2  = (const float*)d_in[2];
    const float* la_w   = (const float*)d_in[3];
    const float* mra_h1 = (const float*)d_in[4];
    const float* mra_v1 = (const float*)d_in[5];
    const float* mra_h2 = (const float*)d_in[6];
    const float* mra_v2 = (const float*)d_in[7];
    const float* g_p1w  = (const float*)d_in[8];
    const float* g_p1b  = (const float*)d_in[9];
    const float* g_c0w  = (const float*)d_in[10];
    const float* g_c0b  = (const float*)d_in[11];
    const float* g_spw  = (const float*)d_in[12];
    const float* g_spb  = (const float*)d_in[13];
    const float* g_c1w  = (const float*)d_in[14];
    const float* g_c1b  = (const float*)d_in[15];
    const float* g_c2w  = (const float*)d_in[16];
    const float* g_c2b  = (const float*)d_in[17];
    const float* g_cw   = (const float*)d_in[18];
    const float* g_cb   = (const float*)d_in[19];
    const float* g_sqw  = (const float*)d_in[20];
    const float* g_sqb  = (const float*)d_in[21];
    const float* g_p2w  = (const float*)d_in[22];
    const float* g_p2b  = (const float*)d_in[23];
    const float* mlp_w1 = (const float*)d_in[24];
    const float* mlp_w2 = (const float*)d_in[25];
    float* outp = (float*)d_out;
    char* ws = (char*)d_ws;

    if (ws_size < (size_t)WS_NEED){
        zero_out_k<<<(out_size + 255)/256, 256, 0, stream>>>(outp, out_size);
        return;
    }

    short* xatt = (short*)(ws + XATT_OFF);   // bf16 px-major (32,4096,256)
    short* tbuf = (short*)(ws + BIG_OFF);    // bf16 px-major (32,4096,256/512)
    short* xpm  = (short*)(ws + XPM_OFF);    // bf16 px-major (32,4096,128) [transient]
    short* yla  = (short*)(ws + YLA_OFF);    // bf16 px-major (32,4096,64)  [transient]
    float* xm   = (float*)(ws + XM_OFF);
    float* msum = (float*)(ws + MSUM_OFF);
    float* x4p  = (float*)(ws + X4P_OFF);
    int*   idx1 = (int*)(ws + IDX1_OFF);
    float* xp   = (float*)(ws + XP_OFF);
    int*   idx2 = (int*)(ws + IDX2_OFF);
    float* hbuf = (float*)(ws + HBUF_OFF);
    float* a1   = (float*)(ws + A1_OFF);
    float* a2   = (float*)(ws + A2_OFF);
    float* a1s  = (float*)(ws + A1S_OFF);
    float* a2s  = (float*)(ws + A2S_OFF);
    float* agg  = (float*)(ws + AGG_OFF);
    float* sig  = (float*)(ws + SIG_OFF);
    float* attn = (float*)(ws + ATTN_OFF);
    float* h2   = (float*)(ws + H2_OFF);
    float* xg   = (float*)(ws + XG_OFF);
    float* p33  = (float*)(ws + P33_OFF);
    float* raw  = (float*)(ws + STATS_OFF);
    float*  raw_pa  = raw;
    float*  raw_la  = raw + 512;
    float*  raw_mra = raw + 640;
    float*  raw_ga  = raw + 768;
    float*  raw_mlp = raw + 896;
    float2* mv_pa   = (float2*)(raw + 1920);
    float2* mv_la   = mv_pa + 256;
    float2* mv_mra  = mv_la + 64;
    float2* mv_ga   = mv_mra + 64;
    float2* mv_mlp  = mv_ga + 64;

    hipMemsetAsync(raw, 0, 1920*sizeof(float), stream);

    // ---- packed weights (PA + LA) live in the p33 region, dead until mp3_k ----
    short* wp_pa1 = (short*)(ws + P33_OFF);          // 256*64
    short* wp_pa2 = wp_pa1 + 256*64;                 // 64*256
    short* wp_la  = wp_pa2 + 64*256;                 // 64*576
    packw_k<<<64,256,0,stream>>>(pa_w1, wp_pa1, 6, 16);
    packw_k<<<64,256,0,stream>>>(pa_w2, wp_pa2, 8, 4);
    packw_la_k<<<144,256,0,stream>>>(la_w, wp_la);

    // ---- transpose x[:,0:128] -> px-major bf16 (feeds PA expand + LA conv) ----
    xpose_pm_k<<<8192,256,0,stream>>>(x, xpm);

    // ---- PA ----
    convmfma_dma_k<4><<<dim3(64,2,32),256,0,stream>>>(xpm,128,0, wp_pa1,64,16, tbuf,256);
    bnstats_pm_k<256><<<dim3(16,32),256,0,stream>>>(tbuf, raw_pa);
    bnfin_k<<<1,256,0,stream>>>(raw_pa, mv_pa, 256, 1.f/131072.f);
    convmfma_reg_k<1,short,2><<<dim3(64,1,32),256,0,stream>>>(tbuf,256,0, mv_pa, wp_pa2,256,4,
                                                              xatt,256,0, x,256,0);

    // ---- LA (implicit-GEMM 3x3 on MFMA) ----
    la_mfma_k<<<dim3(64,1,32),256,0,stream>>>(xpm, wp_la, yla);
    bnstats_pm_k<64><<<dim3(16,32),256,0,stream>>>(yla, raw_la);
    bnfin_k<<<1,256,0,stream>>>(raw_la, mv_la, 64, 1.f/131072.f);
    la_post_pm_k<<<4096,256,0,stream>>>(yla, mv_la, xatt);

    // ---- MRA ---- (p33 reused as maxpool3 buffer; xpm/yla dead from here)
    mp3_k<<<32768,256,0,stream>>>(x, p33);
    blur_k<<<3872,256,0,stream>>>(p33, xm);
    mra_conv_k<<<3872,256,0,stream>>>(xm, mra_h1, mra_v1, mra_h2, mra_v2, msum);
    bnstats_k<float><<<dim3(64,2),256,0,stream>>>(msum,64,0,484, raw_mra);
    bnfin_k<<<1,256,0,stream>>>(raw_mra, mv_mra, 64, 1.f/15488.f);
    mra_gate_pm_k<<<4096,256,0,stream>>>(x, msum, mv_mra, xatt);

    // ---- GA ----
    pool1_k<<<8192,256,0,stream>>>(x, x4p, idx1);
    pool2_k<<<2048,256,0,stream>>>(x4p, xp, idx2);
    ga_proj_k<<<dim3(8,32),256,0,stream>>>(xp, nullptr, g_p1w, g_p1b, hbuf, 64, 1);
    ga_dw5_k<<<2048,256,0,stream>>>(hbuf, g_c0w, g_c0b, a1);
    ga_dw7_k<<<2048,256,0,stream>>>(a1, g_spw, g_spb, a2);
    ga_proj_k<<<dim3(4,32),256,0,stream>>>(a1, nullptr, g_c1w, g_c1b, a1s, 32, 0);
    ga_proj_k<<<dim3(4,32),256,0,stream>>>(a2, nullptr, g_c2w, g_c2b, a2s, 32, 0);
    ga_agg_k<<<32,256,0,stream>>>(a1s, a2s, agg);
    ga_sq_k<<<64,256,0,stream>>>(agg, g_sqw, g_sqb, sig);
    ga_attn_k<<<dim3(8,32),256,0,stream>>>(a1s, a2s, sig, g_cw, g_cb, attn);
    ga_proj_k<<<dim3(8,32),256,0,stream>>>(hbuf, attn, g_p2w, g_p2b, h2, 64, 0);
    ga_unpool1_k<<<8192,256,0,stream>>>(h2, idx2, xg);
    bnstats_k<float><<<dim3(64,4),256,0,stream>>>(xg,64,0,1024, raw_ga);
    bnfin_k<<<1,256,0,stream>>>(raw_ga, mv_ga, 64, 1.f/32768.f);
    ga_out_pm_k<<<4096,256,0,stream>>>(xg, idx1, mv_ga, xatt);

    // ---- MLP residual ---- (p33 region dead again -> pack MLP weights there)
    short* wm1 = (short*)(ws + P33_OFF);             // 512*256
    short* wm2 = wm1 + 512*256;                      // 256*512
    packw_k<<<512,256,0,stream>>>(mlp_w1, wm1, 8, 32);
    packw_k<<<512,256,0,stream>>>(mlp_w2, wm2, 9, 16);
    convmfma_dma_k<4><<<dim3(64,4,32),256,0,stream>>>(xatt,256,0, wm1,256,32, tbuf,512);
    bnstats_pm_k<512><<<dim3(16,32),256,0,stream>>>(tbuf, raw_mlp);
    bnfin_k<<<2,256,0,stream>>>(raw_mlp, mv_mlp, 512, 1.f/131072.f);
    convmfma_reg_k<2,float,4><<<dim3(64,2,32),256,0,stream>>>(tbuf,512,0, mv_mlp, wm2,512,16,
                                                              outp,256,0, x,256,0);
}

// Round 5
// 960.754 us; speedup vs baseline: 2.0454x; 1.0208x over previous
//
#include <hip/hip_runtime.h>
#include <hip/hip_bf16.h>
#include <math.h>

typedef __hip_bfloat16 bf16;
typedef __attribute__((ext_vector_type(4))) float f32x4;
typedef __attribute__((ext_vector_type(8))) short s16x8;
typedef __attribute__((ext_vector_type(4))) short s16x4;

static __device__ __forceinline__ float bits2f(short s){ return __uint_as_float(((unsigned)(unsigned short)s)<<16); }
static __device__ __forceinline__ short bfbits(float f){ bf16 h = __float2bfloat16(f); return *reinterpret_cast<short*>(&h); }
static __device__ __forceinline__ float ldf(float v){ return v; }
static __device__ __forceinline__ float sigm(float v){ return 1.f/(1.f+__expf(-v)); }

#define P_IMG 4096   // 64*64

#define GLDS16(SRC, DST) __builtin_amdgcn_global_load_lds( \
    (__attribute__((address_space(1))) void*)(SRC), \
    (__attribute__((address_space(3))) void*)(DST), 16, 0, 0)

// ---------------- workspace layout (bytes) ----------------
namespace {
constexpr long long XATT_OFF = 0;            // bf16 px-major (32,4096,256) = 64MB
constexpr long long BIG_OFF  = 67108864;     // tbuf: bf16 px-major (32,4096,256) or (32,4096,512)
constexpr long long MISC     = 134217728;
constexpr long long XM_OFF   = MISC;                 // f32 (2048,484)
constexpr long long MSUM_OFF = MISC + 3964928;       // f32 (2048,484)
constexpr long long X4P_OFF  = MISC + 23429120;      // f32 (32,64,1024)
constexpr long long IDX1_OFF = MISC + 31817728;      // i32 (32,64,1024)
constexpr long long XP_OFF   = MISC + 40206336;      // f32 (32,64,256)
constexpr long long IDX2_OFF = MISC + 42303488;      // i32
constexpr long long HBUF_OFF = MISC + 44400640;      // f32 (32,64,256)
constexpr long long A1_OFF   = MISC + 46497792;
constexpr long long A2_OFF   = MISC + 48594944;
constexpr long long A1S_OFF  = MISC + 50692096;      // f32 (32,32,256)
constexpr long long A2S_OFF  = MISC + 51740672;
constexpr long long AGG_OFF  = MISC + 52789248;      // f32 (32,2,256)
constexpr long long SIG_OFF  = MISC + 52854784;
constexpr long long ATTN_OFF = MISC + 52920320;      // f32 (32,64,256)
constexpr long long H2_OFF   = MISC + 55017472;
constexpr long long XG_OFF   = MISC + 57114624;      // f32 (32,64,1024)
constexpr long long P33_OFF  = 201326592;            // f32 (32,64,4096); also hosts packed weights
constexpr long long STATS_OFF= 234881024;
constexpr long long WS_NEED  = 234897408;
// transient (PA/LA phase only, dead once MRA starts): xpm + y_la live in MISC region
constexpr long long XPM_OFF  = MISC;                 // bf16 (32,4096,128) = 32MB
constexpr long long YLA_OFF  = MISC + 33554432;      // bf16 (32,4096,64) = 16MB
}

__global__ __launch_bounds__(256) void zero_out_k(float* __restrict__ o, int n){
    int i = blockIdx.x*256 + threadIdx.x;
    if (i < n) o[i] = 0.f;
}

// ======== weight pre-pack: f32 [O][K] -> bf16 fragment-major ========
// frag layout: idx = ((((k>>6)*2 + kk)*OT16 + (o>>4))*4 + q)*16 + m16)*8 + r
__global__ __launch_bounds__(256) void packw_k(const float* __restrict__ W, short* __restrict__ Wp,
                                               int kshift, int OT16)
{
    int i = blockIdx.x*256 + threadIdx.x;
    int o = i >> kshift;
    int k = i & ((1<<kshift)-1);
    long dest = (((((long)(k>>6)*2 + ((k>>5)&1))*OT16 + (o>>4))*4 + ((k>>3)&3))*16 + (o&15))*8 + (k&7);
    Wp[dest] = bfbits(W[i]);
}

// LA weights (64,64,9) o,c,tap -> packed with k = tap*64 + c, K=576, OT16=4
__global__ __launch_bounds__(256) void packw_la_k(const float* __restrict__ W, short* __restrict__ Wp)
{
    int i = blockIdx.x*256 + threadIdx.x;   // 64*576 = 36864
    int o = i / 576, k = i - o*576;
    int tap = k >> 6, c = k & 63;
    long dest = (((((long)(k>>6)*2 + ((k>>5)&1))*4 + (o>>4))*4 + ((k>>3)&3))*16 + (o&15))*8 + (k&7);
    Wp[dest] = bfbits(W[(o*64 + c)*9 + tap]);
}

// ======== transpose x[b][0..128][px] f32 -> xpm[b][px][128] bf16 ========
__global__ __launch_bounds__(256) void xpose_pm_k(const float* __restrict__ x, short* __restrict__ xpm)
{
    int i = blockIdx.x*256 + threadIdx.x;   // 32*16*4096
    int px = i & 4095, og = (i >> 12) & 15, b = i >> 16;
    s16x8 ov;
    #pragma unroll
    for (int j=0;j<8;j++)
        ov[j] = bfbits(x[((long)b*256 + og*8 + j)*P_IMG + px]);
    *(s16x8*)&xpm[((long)b*P_IMG + px)*128 + og*8] = ov;
}

// ======== generic 1x1 MFMA conv, px-major bf16 in, pipelined GLDS staging ========
// block = 64 px x (32*MT) out-ch. dbuf LDS, counted vmcnt (no vmcnt(0) drain),
// 2 barriers/tile (2nd guards WAR: prefetch DMA vs prev-iter ds_reads).
template<int MT>
__global__ __launch_bounds__(256) void convmfma_dma_k(
    const short* __restrict__ in, int inCtot, int inOff,
    const short* __restrict__ Wp, int K, int OT16,
    short* __restrict__ out, int outC)
{
    static_assert(MT == 4, "vmcnt counts assume MT==4");
    __shared__ __align__(16) short sB[2][64*64];
    const int tid = threadIdx.x;
    const int b = blockIdx.z;
    const int Mbase = blockIdx.y * (32*MT);
    const int pxBase = blockIdx.x * 64;
    const int lane = tid & 63, w = tid >> 6;
    const int n16 = lane & 15, q = lane >> 4;
    const int wm = w >> 1, wn = w & 1;
    const int otBase = (Mbase>>4) + wm*MT;

    f32x4 zero = {0.f,0.f,0.f,0.f};
    f32x4 acc[MT][2];
    #pragma unroll
    for (int mt=0;mt<MT;mt++){ acc[mt][0]=zero; acc[mt][1]=zero; }

    const int drow_lo = lane >> 3;
    const int chunk = lane & 7;
    const int seg0 = w*2, seg1 = w*2 + 1;
    const int row0 = seg0*8 + drow_lo, row1 = seg1*8 + drow_lo;
    const int kg0 = chunk ^ (row0 & 7), kg1 = chunk ^ (row1 & 7);
    const short* src0 = in + ((long)b*P_IMG + pxBase + row0)*inCtot + inOff + kg0*8;
    const short* src1 = in + ((long)b*P_IMG + pxBase + row1)*inCtot + inOff + kg1*8;

    const int NT = K >> 6;
    // prologue: stage tile 0 into buf 0
    GLDS16(src0, (char*)&sB[0][0] + seg0*1024);
    GLDS16(src1, (char*)&sB[0][0] + seg1*1024);

    for (int t = 0; t < NT; t++){
        const int kb = t << 6;
        // region A: weight fragment loads for tile t (oldest VMEM this iter)
        s16x8 afr[2][MT];
        #pragma unroll
        for (int kk=0; kk<2; kk++)
            #pragma unroll
            for (int mt=0; mt<MT; mt++)
                afr[kk][mt] = *(const s16x8*)(Wp + ((((long)t*2 + kk)*OT16 + otBase + mt)*64 + lane)*8);
        __builtin_amdgcn_sched_barrier(0);
        // region B: prefetch tile t+1 into the other buffer, keep it in flight
        if (t+1 < NT){
            GLDS16(src0 + kb + 64, (char*)&sB[(t+1)&1][0] + seg0*1024);
            GLDS16(src1 + kb + 64, (char*)&sB[(t+1)&1][0] + seg1*1024);
            __builtin_amdgcn_sched_barrier(0);
            asm volatile("s_waitcnt vmcnt(10)" ::: "memory");  // drain tile-t DMA; 8 afr + 2 new DMA may fly
        } else {
            __builtin_amdgcn_sched_barrier(0);
            asm volatile("s_waitcnt vmcnt(8)" ::: "memory");   // drain tile-t DMA; 8 afr may fly
        }
        __builtin_amdgcn_sched_barrier(0);
        __builtin_amdgcn_s_barrier();
        __builtin_amdgcn_sched_barrier(0);
        // region C: ds_read + MFMA on buf[t&1]
        const short* sC = &sB[t&1][0];
        #pragma unroll
        for (int kk = 0; kk < 2; kk++){
            s16x8 bfr[2];
            #pragma unroll
            for (int nt=0; nt<2; nt++){
                int n = wn*32 + nt*16 + n16;
                int g = (kk*4 + q) ^ (n & 7);
                bfr[nt] = *(const s16x8*)&sC[n*64 + (g<<3)];
            }
            #pragma unroll
            for (int mt=0; mt<MT; mt++)
                #pragma unroll
                for (int nt=0; nt<2; nt++)
                    acc[mt][nt] = __builtin_amdgcn_mfma_f32_16x16x32_bf16(afr[kk][mt], bfr[nt], acc[mt][nt], 0, 0, 0);
        }
        // barrier2: all waves done reading buf[t&1] before next iter's DMA
        // overwrites buf[(t+2)&1] == buf[t&1]  (WAR guard — Round-3 bug fix)
        __builtin_amdgcn_sched_barrier(0);
        __builtin_amdgcn_s_barrier();
        __builtin_amdgcn_sched_barrier(0);
    }

    #pragma unroll
    for (int mt=0; mt<MT; mt++){
        #pragma unroll
        for (int nt=0; nt<2; nt++){
            int px = pxBase + wn*32 + nt*16 + n16;
            int o0 = Mbase + wm*(MT*16) + mt*16 + q*4;
            s16x4 ov;
            #pragma unroll
            for (int r=0; r<4; r++) ov[r] = bfbits(acc[mt][nt][r]);
            *(s16x4*)&out[((long)b*P_IMG + px)*outC + o0] = ov;
        }
    }
}

// ======== LA 3x3 conv as implicit GEMM: K = 9 taps x 64 ch, pipelined ========
__global__ __launch_bounds__(256) void la_mfma_k(
    const short* __restrict__ xpm,   // [b][4096][128], LA slice at +64
    const short* __restrict__ Wp,    // packed K=576, OT16=4
    short* __restrict__ y)           // [b][4096][64] bf16
{
    __shared__ __align__(16) short sB[2][64*64];
    const int tid = threadIdx.x;
    const int b = blockIdx.z;
    const int hRow = blockIdx.x;
    const int pxBase = hRow*64;
    const int lane = tid & 63, w = tid >> 6;
    const int n16 = lane & 15, q = lane >> 4;
    const int wm = w >> 1, wn = w & 1;
    const int otBase = wm*2;

    f32x4 zero = {0.f,0.f,0.f,0.f};
    f32x4 acc[2][2];
    acc[0][0]=zero; acc[0][1]=zero; acc[1][0]=zero; acc[1][1]=zero;

    const int srow = tid >> 3, schunk = tid & 7;
    const int kgA = schunk ^ (srow & 7);   // same for srow and srow+32

    auto tapload = [&](int tap, s16x8& v0, s16x8& v1){
        int hh = hRow + (tap/3) - 1;
        int dw = (tap%3) - 1;
        bool hok = (unsigned)hh < 64u;
        s16x8 z = {0,0,0,0,0,0,0,0};
        v0 = z; v1 = z;
        int w0 = srow + dw, w1 = 32 + srow + dw;
        if (hok && (unsigned)w0 < 64u)
            v0 = *(const s16x8*)(xpm + ((long)b*P_IMG + hh*64 + w0)*128 + 64 + kgA*8);
        if (hok && (unsigned)w1 < 64u)
            v1 = *(const s16x8*)(xpm + ((long)b*P_IMG + hh*64 + w1)*128 + 64 + kgA*8);
    };

    s16x8 cv0, cv1;
    tapload(0, cv0, cv1);

    for (int tap = 0; tap < 9; tap++){
        s16x8 nv0 = cv0, nv1 = cv1;
        if (tap+1 < 9) tapload(tap+1, nv0, nv1);
        // stage current tap
        *(s16x8*)&sB[tap&1][srow*64 + schunk*8]      = cv0;
        *(s16x8*)&sB[tap&1][(32+srow)*64 + schunk*8] = cv1;
        asm volatile("s_waitcnt lgkmcnt(0)" ::: "memory");
        __builtin_amdgcn_sched_barrier(0);
        __builtin_amdgcn_s_barrier();
        __builtin_amdgcn_sched_barrier(0);
        const short* sC = &sB[tap&1][0];
        #pragma unroll
        for (int kk = 0; kk < 2; kk++){
            s16x8 afr[2], bfr[2];
            #pragma unroll
            for (int mt=0; mt<2; mt++)
                afr[mt] = *(const s16x8*)(Wp + ((((long)tap*2 + kk)*4 + otBase + mt)*64 + lane)*8);
            #pragma unroll
            for (int nt=0; nt<2; nt++){
                int n = wn*32 + nt*16 + n16;
                int g = (kk*4 + q) ^ (n & 7);
                bfr[nt] = *(const s16x8*)&sC[n*64 + (g<<3)];
            }
            #pragma unroll
            for (int mt=0; mt<2; mt++)
                #pragma unroll
                for (int nt=0; nt<2; nt++)
                    acc[mt][nt] = __builtin_amdgcn_mfma_f32_16x16x32_bf16(afr[mt], bfr[nt], acc[mt][nt], 0, 0, 0);
        }
        // barrier2: WAR guard before next tap overwrites the other buffer
        __builtin_amdgcn_sched_barrier(0);
        __builtin_amdgcn_s_barrier();
        __builtin_amdgcn_sched_barrier(0);
        cv0 = nv0; cv1 = nv1;
    }

    #pragma unroll
    for (int mt=0; mt<2; mt++){
        #pragma unroll
        for (int nt=0; nt<2; nt++){
            int px = pxBase + wn*32 + nt*16 + n16;
            int o0 = wm*32 + mt*16 + q*4;
            s16x4 ov;
            #pragma unroll
            for (int r=0; r<4; r++) ov[r] = bfbits(acc[mt][nt][r]);
            *(s16x4*)&y[((long)b*P_IMG + px)*64 + o0] = ov;
        }
    }
}

// ======== BN+ReLU convs (PA gate epi=1, MLP2 epi=2): px-major bf16 in, pipelined reg staging ========
template<int EPI, typename TOUT, int MT>
__global__ __launch_bounds__(256) void convmfma_reg_k(
    const short* __restrict__ in, int inCtot, int inOff,
    const float2* __restrict__ stats,
    const short* __restrict__ Wp, int K, int OT16,
    TOUT* __restrict__ out, int outC, int outOff,
    const float* __restrict__ aux, int auxC, int auxOff)
{
    __shared__ __align__(16) short sB[2][64*64];
    const int tid = threadIdx.x;
    const int b = blockIdx.z;
    const int Mbase = blockIdx.y * (32*MT);
    const int pxBase = blockIdx.x * 64;
    const int lane = tid & 63, w = tid >> 6;
    const int n16 = lane & 15, q = lane >> 4;
    const int wm = w >> 1, wn = w & 1;
    const int otBase = (Mbase>>4) + wm*MT;

    f32x4 zero = {0.f,0.f,0.f,0.f};
    f32x4 acc[MT][2];
    #pragma unroll
    for (int mt=0;mt<MT;mt++){ acc[mt][0]=zero; acc[mt][1]=zero; }

    const int srow = tid >> 3, schunk = tid & 7;
    const int skg = schunk ^ (srow & 7);
    const short* inrow0 = in + ((long)b*P_IMG + pxBase + srow)*inCtot + inOff + skg*8;
    const short* inrow1 = in + ((long)b*P_IMG + pxBase + 32 + srow)*inCtot + inOff + skg*8;
    const float2* stp = stats + skg*8;

    const int NT = K >> 6;
    // prologue loads for tile 0
    s16x8 rv0 = *(const s16x8*)(inrow0);
    s16x8 rv1 = *(const s16x8*)(inrow1);
    const f32x4* sp0 = (const f32x4*)(stp);
    f32x4 p0 = sp0[0], p1 = sp0[1], p2 = sp0[2], p3 = sp0[3];

    for (int t = 0; t < NT; t++){
        const int kb = t << 6;
        // prefetch tile t+1 (issued before BN so HBM latency hides under MFMA)
        s16x8 nrv0 = rv0, nrv1 = rv1;
        f32x4 q0 = p0, q1 = p1, q2 = p2, q3 = p3;
        if (t+1 < NT){
            nrv0 = *(const s16x8*)(inrow0 + kb + 64);
            nrv1 = *(const s16x8*)(inrow1 + kb + 64);
            const f32x4* np = (const f32x4*)(stp + kb + 64);
            q0 = np[0]; q1 = np[1]; q2 = np[2]; q3 = np[3];
        }
        float mm[8] = {p0[0],p0[2],p1[0],p1[2],p2[0],p2[2],p3[0],p3[2]};
        float iv[8] = {p0[1],p0[3],p1[1],p1[3],p2[1],p2[3],p3[1],p3[3]};
        s16x8 sg0, sg1;
        #pragma unroll
        for (int j=0;j<8;j++){
            float f = bits2f(rv0[j]);
            f = (f - mm[j])*iv[j];
            sg0[j] = bfbits(fmaxf(f, 0.f));
        }
        #pragma unroll
        for (int j=0;j<8;j++){
            float f = bits2f(rv1[j]);
            f = (f - mm[j])*iv[j];
            sg1[j] = bfbits(fmaxf(f, 0.f));
        }
        *(s16x8*)&sB[t&1][srow*64 + schunk*8]      = sg0;
        *(s16x8*)&sB[t&1][(32+srow)*64 + schunk*8] = sg1;
        asm volatile("s_waitcnt lgkmcnt(0)" ::: "memory");
        __builtin_amdgcn_sched_barrier(0);
        __builtin_amdgcn_s_barrier();
        __builtin_amdgcn_sched_barrier(0);
        const short* sC = &sB[t&1][0];
        #pragma unroll
        for (int kk = 0; kk < 2; kk++){
            s16x8 afr[MT], bfr[2];
            #pragma unroll
            for (int mt=0; mt<MT; mt++)
                afr[mt] = *(const s16x8*)(Wp + ((((long)t*2 + kk)*OT16 + otBase + mt)*64 + lane)*8);
            #pragma unroll
            for (int nt=0; nt<2; nt++){
                int n = wn*32 + nt*16 + n16;
                int g = (kk*4 + q) ^ (n & 7);
                bfr[nt] = *(const s16x8*)&sC[n*64 + (g<<3)];
            }
            #pragma unroll
            for (int mt=0; mt<MT; mt++)
                #pragma unroll
                for (int nt=0; nt<2; nt++)
                    acc[mt][nt] = __builtin_amdgcn_mfma_f32_16x16x32_bf16(afr[mt], bfr[nt], acc[mt][nt], 0, 0, 0);
        }
        // barrier2: WAR guard before next iter's ds_write to the other buffer
        __builtin_amdgcn_sched_barrier(0);
        __builtin_amdgcn_s_barrier();
        __builtin_amdgcn_sched_barrier(0);
        rv0 = nrv0; rv1 = nrv1;
        p0 = q0; p1 = q1; p2 = q2; p3 = q3;
    }

    #pragma unroll
    for (int mt=0; mt<MT; mt++){
        #pragma unroll
        for (int nt=0; nt<2; nt++){
            int px = pxBase + wn*32 + nt*16 + n16;
            int o0 = Mbase + wm*(MT*16) + mt*16 + q*4;
            if constexpr (EPI == 1){
                s16x4 ov;
                #pragma unroll
                for (int r=0; r<4; r++){
                    float av = aux[((long)b*auxC + auxOff + o0 + r)*P_IMG + px];
                    ov[r] = bfbits(av * sigm(acc[mt][nt][r]));
                }
                *(s16x4*)&(((short*)out)[((long)b*P_IMG + px)*outC + outOff + o0]) = ov;
            } else {
                #pragma unroll
                for (int r=0; r<4; r++){
                    int o = o0 + r;
                    float av = aux[((long)b*auxC + auxOff + o)*P_IMG + px];
                    out[((long)b*outC + outOff + o)*P_IMG + px] = av + acc[mt][nt][r];
                }
            }
        }
    }
}

// ============ BN batch-stats: px-major bf16 [b][4096][C] ============
template<int C>
__global__ __launch_bounds__(256) void bnstats_pm_k(const short* __restrict__ in, float* __restrict__ sums)
{
    constexpr int CH8 = C/8;
    constexpr int PL  = 256/CH8;
    __shared__ float accs[2*C];
    const int t = threadIdx.x;
    for (int i=t;i<2*C;i+=256) accs[i]=0.f;
    __syncthreads();
    const int chunk = t & (CH8-1), pl = t / CH8;
    const int b = blockIdx.y;
    float s[8], s2[8];
    #pragma unroll
    for (int j=0;j<8;j++){ s[j]=0.f; s2[j]=0.f; }
    for (int px = blockIdx.x*256 + pl; px < (blockIdx.x+1)*256; px += PL){
        s16x8 v = *(const s16x8*)&in[((long)b*P_IMG + px)*C + chunk*8];
        #pragma unroll
        for (int j=0;j<8;j++){
            float f = bits2f(v[j]);
            s[j] += f; s2[j] = fmaf(f,f,s2[j]);
        }
    }
    #pragma unroll
    for (int j=0;j<8;j++){
        atomicAdd(&accs[(chunk*8+j)*2],   s[j]);
        atomicAdd(&accs[(chunk*8+j)*2+1], s2[j]);
    }
    __syncthreads();
    for (int i=t;i<2*C;i+=256) atomicAdd(&sums[i], accs[i]);
}

// ============ BN batch-stats: c-major f32 (msum, xg) ============
template<typename T>
__global__ __launch_bounds__(256) void bnstats_k(const T* __restrict__ in, int Ctot, int cOff, int Pn,
                                                 float* __restrict__ sums)
{
    const int c = blockIdx.x;
    float s=0.f, s2=0.f;
    for (int b=0;b<32;b++){
        const T* qp = in + ((long)b*Ctot + cOff + c)*Pn;
        for (int p = blockIdx.y*256 + threadIdx.x; p < Pn; p += gridDim.y*256){
            float v = ldf(qp[p]);
            s += v; s2 = fmaf(v,v,s2);
        }
    }
    __shared__ float r1[256], r2[256];
    r1[threadIdx.x]=s; r2[threadIdx.x]=s2;
    __syncthreads();
    for (int k=128;k>0;k>>=1){
        if (threadIdx.x<k){ r1[threadIdx.x]+=r1[threadIdx.x+k]; r2[threadIdx.x]+=r2[threadIdx.x+k]; }
        __syncthreads();
    }
    if (threadIdx.x==0){ atomicAdd(&sums[2*c], r1[0]); atomicAdd(&sums[2*c+1], r2[0]); }
}

__global__ __launch_bounds__(256) void bnfin_k(const float* __restrict__ sums, float2* __restrict__ minv,
                                               int C, float invN)
{
    int c = blockIdx.x*256 + threadIdx.x;
    if (c < C){
        float m = sums[2*c]*invN;
        float var = sums[2*c+1]*invN - m*m;
        minv[c] = make_float2(m, 1.f/sqrtf(var + 1e-5f));
    }
}

__global__ __launch_bounds__(256) void la_post_pm_k(const short* __restrict__ y, const float2* __restrict__ minv,
                                                    short* __restrict__ xatt)
{
    int i = blockIdx.x*256 + threadIdx.x;
    int px = i & 4095, og = (i >> 12) & 7, b = i >> 15;
    s16x8 yv = *(const s16x8*)&y[((long)b*P_IMG + px)*64 + og*8];
    s16x8 ov;
    #pragma unroll
    for (int j=0;j<8;j++){
        float2 st = minv[og*8 + j];
        float v = (bits2f(yv[j]) - st.x)*st.y;
        ov[j] = bfbits(fmaxf(v, 0.f));
    }
    *(s16x8*)&xatt[((long)b*P_IMG + px)*256 + 64 + og*8] = ov;
}

// ============ MRA ============
__global__ __launch_bounds__(256) void mp3_k(const float* __restrict__ x, float* __restrict__ mp){
    int i = blockIdx.x*256 + threadIdx.x;
    int b = i >> 18, c = (i >> 12) & 63, p = i & 4095;
    int h = p >> 6, wc = p & 63;
    const float* xb = x + ((long)b*256 + 128 + c)*P_IMG;
    float m = -3.4e38f;
    #pragma unroll
    for (int dh=-1; dh<=1; dh++){
        int hh = h+dh; if ((unsigned)hh>=64u) continue;
        #pragma unroll
        for (int dw=-1; dw<=1; dw++){
            int ww = wc+dw; if ((unsigned)ww>=64u) continue;
            m = fmaxf(m, xb[hh*64+ww]);
        }
    }
    mp[i] = m;
}

__global__ __launch_bounds__(256) void blur_k(const float* __restrict__ mp, float* __restrict__ xm){
    int idx = blockIdx.x*256 + threadIdx.x;
    int oj = idx % 22; int t = idx / 22; int oi = t % 22; int bc = t / 22;
    const float* mb = mp + (long)bc * P_IMG;
    const float fw[4] = {1.f,3.f,3.f,1.f};
    float s = 0.f;
    #pragma unroll
    for (int u=0;u<4;u++){
        int r = 3*oi - 1 + u;
        r = r < 0 ? -r : (r > 63 ? 126 - r : r);
        float rs = 0.f;
        #pragma unroll
        for (int v=0; v<4; v++){
            int qq = 3*oj - 1 + v;
            qq = qq < 0 ? -qq : (qq > 63 ? 126 - qq : qq);
            rs = fmaf(fw[v], mb[r*64+qq], rs);
        }
        s = fmaf(fw[u], rs, s);
    }
    xm[idx] = s * (1.f/64.f);
}

// ==== fused MRA conv: strips (h1,v1) + sheared strips (h2,v2), all from xm ====
__global__ __launch_bounds__(256) void mra_conv_k(const float* __restrict__ xm,
                                                  const float* __restrict__ wh1, const float* __restrict__ wv1,
                                                  const float* __restrict__ wh2, const float* __restrict__ wv2,
                                                  float* __restrict__ msum)
{
    int idx = blockIdx.x*256 + threadIdx.x;   // 2048*484
    int j = idx % 22; int t = idx / 22; int i = t % 22; int bc = t / 22; int c = bc & 63;
    const float* xb = xm + (long)bc*484;
    float s = 0.f;
    // h1 strip 11x3
    #pragma unroll
    for (int u=0;u<11;u++){
        int ii = i + u - 5; if ((unsigned)ii >= 22u) continue;
        #pragma unroll
        for (int v=0;v<3;v++){
            int jj = j + v - 1; if ((unsigned)jj >= 22u) continue;
            s = fmaf(wh1[c*33 + u*3 + v], xb[ii*22+jj], s);
        }
    }
    // v1 strip 3x11
    #pragma unroll
    for (int u=0;u<3;u++){
        int ii = i + u - 1; if ((unsigned)ii >= 22u) continue;
        #pragma unroll
        for (int v=0;v<11;v++){
            int jj = j + v - 5; if ((unsigned)jj >= 22u) continue;
            s = fmaf(wv1[c*33 + u*11 + v], xb[ii*22+jj], s);
        }
    }
    // h2 sheared strip
    {
        int f = i*44 + j; int r = f/43; int q = f - 43*r;
        #pragma unroll
        for (int u=0;u<11;u++){
            int a = r + u - 5; if ((unsigned)a >= 22u) continue;
            #pragma unroll
            for (int v=0;v<3;v++){
                int bcol = q + v - 1; if ((unsigned)bcol >= 43u) continue;
                int g = a*43 + bcol; int rr = g/44; int qq = g - 44*rr;
                if (qq < 22) s = fmaf(wh2[c*33 + u*3 + v], xb[rr*22+qq], s);
            }
        }
    }
    // v2 sheared strip
    {
        int g = j*44 + i; int r = g/43; int q = g - 43*r;
        #pragma unroll
        for (int u=0;u<3;u++){
            int a = q + u - 1; if ((unsigned)a >= 43u) continue;
            #pragma unroll
            for (int v=0;v<11;v++){
                int bcol = r + v - 5; if ((unsigned)bcol >= 22u) continue;
                int g2 = bcol*43 + a; int rr = g2/44; int qq = g2 - 44*rr;
                if (qq < 22) s = fmaf(wv2[c*33 + u*11 + v], xb[qq*22+rr], s);
            }
        }
    }
    msum[idx] = s;
}

__global__ __launch_bounds__(256) void mra_gate_pm_k(const float* __restrict__ x, const float* __restrict__ msum,
                                                     const float2* __restrict__ minv, short* __restrict__ xatt)
{
    int i = blockIdx.x*256 + threadIdx.x;
    int px = i & 4095, og = (i >> 12) & 7, b = i >> 15;
    int h = px >> 6, wcol = px & 63;
    int ri = (h*22) >> 6, ci = (wcol*22) >> 6;
    s16x8 ov;
    #pragma unroll
    for (int j=0;j<8;j++){
        int c = og*8 + j;
        float g = msum[((long)b*64 + c)*484 + ri*22 + ci];
        float2 st = minv[c];
        g = sigm((g - st.x)*st.y);
        float xv = x[((long)b*256 + 128 + c)*P_IMG + px];
        ov[j] = bfbits(xv * g);
    }
    *(s16x8*)&xatt[((long)b*P_IMG + px)*256 + 128 + og*8] = ov;
}

// ============ GA ============
__global__ __launch_bounds__(256) void pool1_k(const float* __restrict__ x, float* __restrict__ x4p,
                                               int* __restrict__ idx1)
{
    int i = blockIdx.x*256 + threadIdx.x;
    int b = i >> 16, c = (i >> 10) & 63, s = i & 1023;
    int y = s >> 5, xc = s & 31;
    const float* xb = x + ((long)b*256 + 192 + c)*P_IMG;
    float v00 = xb[(2*y)*64 + 2*xc];
    float v01 = xb[(2*y)*64 + 2*xc + 1];
    float v10 = xb[(2*y+1)*64 + 2*xc];
    float v11 = xb[(2*y+1)*64 + 2*xc + 1];
    float best = v00; int bi = 0;
    if (v01 > best){ best = v01; bi = 1; }
    if (v10 > best){ best = v10; bi = 2; }
    if (v11 > best){ best = v11; bi = 3; }
    x4p[i] = best; idx1[i] = bi;
}

__global__ __launch_bounds__(256) void pool2_k(const float* __restrict__ x4p, float* __restrict__ xp,
                                               int* __restrict__ idx2)
{
    int i = blockIdx.x*256 + threadIdx.x;
    int b = i >> 14, c = (i >> 8) & 63, s = i & 255;
    int y = s >> 4, xc = s & 15;
    const float* xb = x4p + ((long)b*64 + c)*1024;
    float v00 = xb[(2*y)*32 + 2*xc];
    float v01 = xb[(2*y)*32 + 2*xc + 1];
    float v10 = xb[(2*y+1)*32 + 2*xc];
    float v11 = xb[(2*y+1)*32 + 2*xc + 1];
    float best = v00; int bi = 0;
    if (v01 > best){ best = v01; bi = 1; }
    if (v10 > best){ best = v10; bi = 2; }
    if (v11 > best){ best = v11; bi = 3; }
    xp[i] = best; idx2[i] = bi;
}

__global__ __launch_bounds__(256) void ga_proj_k(const float* __restrict__ in, const float* __restrict__ mul,
                                                 const float* __restrict__ w, const float* __restrict__ bias,
                                                 float* __restrict__ out, int Cout, int relu)
{
    int s = threadIdx.x, og = blockIdx.x, b = blockIdx.y;
    float acc[8];
    #pragma unroll
    for (int j=0;j<8;j++) acc[j]=0.f;
    for (int c=0;c<64;c++){
        float v = in[((long)b*64 + c)*256 + s];
        if (mul) v *= mul[((long)b*64 + c)*256 + s];
        #pragma unroll
        for (int j=0;j<8;j++) acc[j] = fmaf(v, w[(og*8 + j)*64 + c], acc[j]);
    }
    #pragma unroll
    for (int j=0;j<8;j++){
        int o = og*8 + j;
        float val = acc[j] + bias[o];
        if (relu) val = fmaxf(val, 0.f);
        out[((long)b*Cout + o)*256 + s] = val;
    }
}

__global__ __launch_bounds__(256) void ga_dw5_k(const float* __restrict__ h, const float* __restrict__ w,
                                                const float* __restrict__ bias, float* __restrict__ a1)
{
    int i = blockIdx.x*256 + threadIdx.x;
    int b = i >> 14, c = (i >> 8) & 63, s = i & 255;
    int y = s >> 4, x = s & 15;
    const float* hb = h + ((long)b*64 + c)*256;
    float acc = bias[c];
    #pragma unroll
    for (int u=0;u<5;u++){
        int yy = y + u - 2; if ((unsigned)yy >= 16u) continue;
        #pragma unroll
        for (int v=0;v<5;v++){
            int xx = x + v - 2; if ((unsigned)xx >= 16u) continue;
            acc = fmaf(w[c*25 + u*5 + v], hb[yy*16 + xx], acc);
        }
    }
    a1[i] = acc;
}

__global__ __launch_bounds__(256) void ga_dw7_k(const float* __restrict__ a1, const float* __restrict__ w,
                                                const float* __restrict__ bias, float* __restrict__ a2)
{
    int i = blockIdx.x*256 + threadIdx.x;
    int b = i >> 14, c = (i >> 8) & 63, s = i & 255;
    int y = s >> 4, x = s & 15;
    const float* ab = a1 + ((long)b*64 + c)*256;
    float acc = bias[c];
    #pragma unroll
    for (int u=0;u<7;u++){
        int yy = y + 3*(u-3); if ((unsigned)yy >= 16u) continue;
        #pragma unroll
        for (int v=0;v<7;v++){
            int xx = x + 3*(v-3); if ((unsigned)xx >= 16u) continue;
            acc = fmaf(w[c*49 + u*7 + v], ab[yy*16 + xx], acc);
        }
    }
    a2[i] = acc;
}

__global__ __launch_bounds__(256) void ga_agg_k(const float* __restrict__ a1s, const float* __restrict__ a2s,
                                                float* __restrict__ agg)
{
    int i = blockIdx.x*256 + threadIdx.x;
    int b = i >> 8, s = i & 255;
    float sum = 0.f, mx = -3.4e38f;
    for (int c=0;c<32;c++){
        float v = a1s[((long)b*32 + c)*256 + s];
        sum += v; mx = fmaxf(mx, v);
    }
    for (int c=0;c<32;c++){
        float v = a2s[((long)b*32 + c)*256 + s];
        sum += v; mx = fmaxf(mx, v);
    }
    agg[((long)b*2 + 0)*256 + s] = sum * (1.f/64.f);
    agg[((long)b*2 + 1)*256 + s] = mx;
}

__global__ __launch_bounds__(256) void ga_sq_k(const float* __restrict__ agg, const float* __restrict__ w,
                                               const float* __restrict__ bias, float* __restrict__ sig)
{
    int i = blockIdx.x*256 + threadIdx.x;
    int b = i >> 9, o = (i >> 8) & 1, s = i & 255;
    int y = s >> 4, x = s & 15;
    float acc = bias[o];
    for (int ic=0; ic<2; ic++){
        const float* ab = agg + ((long)b*2 + ic)*256;
        #pragma unroll
        for (int u=0;u<7;u++){
            int yy = y + u - 3; if ((unsigned)yy >= 16u) continue;
            #pragma unroll
            for (int v=0;v<7;v++){
                int xx = x + v - 3; if ((unsigned)xx >= 16u) continue;
                acc = fmaf(w[((o*2 + ic)*7 + u)*7 + v], ab[yy*16 + xx], acc);
            }
        }
    }
    sig[i] = sigm(acc);
}

__global__ __launch_bounds__(256) void ga_attn_k(const float* __restrict__ a1s, const float* __restrict__ a2s,
                                                 const float* __restrict__ sig, const float* __restrict__ w,
                                                 const float* __restrict__ bias, float* __restrict__ attn)
{
    int s = threadIdx.x, og = blockIdx.x, b = blockIdx.y;
    float s0 = sig[((long)b*2 + 0)*256 + s];
    float s1 = sig[((long)b*2 + 1)*256 + s];
    float acc[8];
    #pragma unroll
    for (int j=0;j<8;j++) acc[j]=0.f;
    for (int c=0;c<32;c++){
        float v = a1s[((long)b*32 + c)*256 + s]*s0 + a2s[((long)b*32 + c)*256 + s]*s1;
        #pragma unroll
        for (int j=0;j<8;j++) acc[j] = fmaf(v, w[(og*8 + j)*32 + c], acc[j]);
    }
    #pragma unroll
    for (int j=0;j<8;j++){
        int o = og*8 + j;
        attn[((long)b*64 + o)*256 + s] = acc[j] + bias[o];
    }
}

__global__ __launch_bounds__(256) void ga_unpool1_k(const float* __restrict__ h2, const int* __restrict__ idx2,
                                                    float* __restrict__ xg)
{
    int i = blockIdx.x*256 + threadIdx.x;
    int b = i >> 16, c = (i >> 10) & 63, s = i & 1023;
    int Y = s >> 5, X = s & 31;
    int slot = ((Y & 1) << 1) | (X & 1);
    long pi = ((long)b*64 + c)*256 + (Y >> 1)*16 + (X >> 1);
    xg[i] = (idx2[pi] == slot) ? h2[pi] : 0.f;
}

__global__ __launch_bounds__(256) void ga_out_pm_k(const float* __restrict__ xg, const int* __restrict__ idx1,
                                                   const float2* __restrict__ minv, short* __restrict__ xatt)
{
    int i = blockIdx.x*256 + threadIdx.x;
    int px = i & 4095, og = (i >> 12) & 7, b = i >> 15;
    int hh = px >> 6, ww = px & 63;
    int slot = ((hh & 1) << 1) | (ww & 1);
    s16x8 ov;
    #pragma unroll
    for (int j=0;j<8;j++){
        int c = og*8 + j;
        long pi = ((long)b*64 + c)*1024 + (hh >> 1)*32 + (ww >> 1);
        float v = 0.f;
        if (idx1[pi] == slot){
            float2 st = minv[c];
            v = (xg[pi] - st.x)*st.y;
        }
        ov[j] = bfbits(v);
    }
    *(s16x8*)&xatt[((long)b*P_IMG + px)*256 + 192 + og*8] = ov;
}

// ============================================================================
extern "C" void kernel_launch(void* const* d_in, const int* in_sizes, int n_in,
                              void* d_out, int out_size, void* d_ws, size_t ws_size,
                              hipStream_t stream)
{
    const float* x      = (const float*)d_in[0];
    const float* pa_w1  = (const float*)d_in[1];
    const float* pa_w2  = (const float*)d_in[2];
    const float* la_w   = (const float*)d_in[3];
    const float* mra_h1 = (const float*)d_in[4];
    const float* mra_v1 = (const float*)d_in[5];
    const float* mra_h2 = (const float*)d_in[6];
    const float* mra_v2 = (const float*)d_in[7];
    const float* g_p1w  = (const float*)d_in[8];
    const float* g_p1b  = (const float*)d_in[9];
    const float* g_c0w  = (const float*)d_in[10];
    const float* g_c0b  = (const float*)d_in[11];
    const float* g_spw  = (const float*)d_in[12];
    const float* g_spb  = (const float*)d_in[13];
    const float* g_c1w  = (const float*)d_in[14];
    const float* g_c1b  = (const float*)d_in[15];
    const float* g_c2w  = (const float*)d_in[16];
    const float* g_c2b  = (const float*)d_in[17];
    const float* g_cw   = (const float*)d_in[18];
    const float* g_cb   = (const float*)d_in[19];
    const float* g_sqw  = (const float*)d_in[20];
    const float* g_sqb  = (const float*)d_in[21];
    const float* g_p2w  = (const float*)d_in[22];
    const float* g_p2b  = (const float*)d_in[23];
    const float* mlp_w1 = (const float*)d_in[24];
    const float* mlp_w2 = (const float*)d_in[25];
    float* outp = (float*)d_out;
    char* ws = (char*)d_ws;

    if (ws_size < (size_t)WS_NEED){
        zero_out_k<<<(out_size + 255)/256, 256, 0, stream>>>(outp, out_size);
        return;
    }

    short* xatt = (short*)(ws + XATT_OFF);   // bf16 px-major (32,4096,256)
    short* tbuf = (short*)(ws + BIG_OFF);    // bf16 px-major (32,4096,256/512)
    short* xpm  = (short*)(ws + XPM_OFF);    // bf16 px-major (32,4096,128) [transient]
    short* yla  = (short*)(ws + YLA_OFF);    // bf16 px-major (32,4096,64)  [transient]
    float* xm   = (float*)(ws + XM_OFF);
    float* msum = (float*)(ws + MSUM_OFF);
    float* x4p  = (float*)(ws + X4P_OFF);
    int*   idx1 = (int*)(ws + IDX1_OFF);
    float* xp   = (float*)(ws + XP_OFF);
    int*   idx2 = (int*)(ws + IDX2_OFF);
    float* hbuf = (float*)(ws + HBUF_OFF);
    float* a1   = (float*)(ws + A1_OFF);
    float* a2   = (float*)(ws + A2_OFF);
    float* a1s  = (float*)(ws + A1S_OFF);
    float* a2s  = (float*)(ws + A2S_OFF);
    float* agg  = (float*)(ws + AGG_OFF);
    float* sig  = (float*)(ws + SIG_OFF);
    float* attn = (float*)(ws + ATTN_OFF);
    float* h2   = (float*)(ws + H2_OFF);
    float* xg   = (float*)(ws + XG_OFF);
    float* p33  = (float*)(ws + P33_OFF);
    float* raw  = (float*)(ws + STATS_OFF);
    float*  raw_pa  = raw;
    float*  raw_la  = raw + 512;
    float*  raw_mra = raw + 640;
    float*  raw_ga  = raw + 768;
    float*  raw_mlp = raw + 896;
    float2* mv_pa   = (float2*)(raw + 1920);
    float2* mv_la   = mv_pa + 256;
    float2* mv_mra  = mv_la + 64;
    float2* mv_ga   = mv_mra + 64;
    float2* mv_mlp  = mv_ga + 64;

    hipMemsetAsync(raw, 0, 1920*sizeof(float), stream);

    // ---- packed weights (PA + LA) live in the p33 region, dead until mp3_k ----
    short* wp_pa1 = (short*)(ws + P33_OFF);          // 256*64
    short* wp_pa2 = wp_pa1 + 256*64;                 // 64*256
    short* wp_la  = wp_pa2 + 64*256;                 // 64*576
    packw_k<<<64,256,0,stream>>>(pa_w1, wp_pa1, 6, 16);
    packw_k<<<64,256,0,stream>>>(pa_w2, wp_pa2, 8, 4);
    packw_la_k<<<144,256,0,stream>>>(la_w, wp_la);

    // ---- transpose x[:,0:128] -> px-major bf16 (feeds PA expand + LA conv) ----
    xpose_pm_k<<<8192,256,0,stream>>>(x, xpm);

    // ---- PA ----
    convmfma_dma_k<4><<<dim3(64,2,32),256,0,stream>>>(xpm,128,0, wp_pa1,64,16, tbuf,256);
    bnstats_pm_k<256><<<dim3(16,32),256,0,stream>>>(tbuf, raw_pa);
    bnfin_k<<<1,256,0,stream>>>(raw_pa, mv_pa, 256, 1.f/131072.f);
    convmfma_reg_k<1,short,2><<<dim3(64,1,32),256,0,stream>>>(tbuf,256,0, mv_pa, wp_pa2,256,4,
                                                              xatt,256,0, x,256,0);

    // ---- LA (implicit-GEMM 3x3 on MFMA) ----
    la_mfma_k<<<dim3(64,1,32),256,0,stream>>>(xpm, wp_la, yla);
    bnstats_pm_k<64><<<dim3(16,32),256,0,stream>>>(yla, raw_la);
    bnfin_k<<<1,256,0,stream>>>(raw_la, mv_la, 64, 1.f/131072.f);
    la_post_pm_k<<<4096,256,0,stream>>>(yla, mv_la, xatt);

    // ---- MRA ---- (p33 reused as maxpool3 buffer; xpm/yla dead from here)
    mp3_k<<<32768,256,0,stream>>>(x, p33);
    blur_k<<<3872,256,0,stream>>>(p33, xm);
    mra_conv_k<<<3872,256,0,stream>>>(xm, mra_h1, mra_v1, mra_h2, mra_v2, msum);
    bnstats_k<float><<<dim3(64,2),256,0,stream>>>(msum,64,0,484, raw_mra);
    bnfin_k<<<1,256,0,stream>>>(raw_mra, mv_mra, 64, 1.f/15488.f);
    mra_gate_pm_k<<<4096,256,0,stream>>>(x, msum, mv_mra, xatt);

    // ---- GA ----
    pool1_k<<<8192,256,0,stream>>>(x, x4p, idx1);
    pool2_k<<<2048,256,0,stream>>>(x4p, xp, idx2);
    ga_proj_k<<<dim3(8,32),256,0,stream>>>(xp, nullptr, g_p1w, g_p1b, hbuf, 64, 1);
    ga_dw5_k<<<2048,256,0,stream>>>(hbuf, g_c0w, g_c0b, a1);
    ga_dw7_k<<<2048,256,0,stream>>>(a1, g_spw, g_spb, a2);
    ga_proj_k<<<dim3(4,32),256,0,stream>>>(a1, nullptr, g_c1w, g_c1b, a1s, 32, 0);
    ga_proj_k<<<dim3(4,32),256,0,stream>>>(a2, nullptr, g_c2w, g_c2b, a2s, 32, 0);
    ga_agg_k<<<32,256,0,stream>>>(a1s, a2s, agg);
    ga_sq_k<<<64,256,0,stream>>>(agg, g_sqw, g_sqb, sig);
    ga_attn_k<<<dim3(8,32),256,0,stream>>>(a1s, a2s, sig, g_cw, g_cb, attn);
    ga_proj_k<<<dim3(8,32),256,0,stream>>>(hbuf, attn, g_p2w, g_p2b, h2, 64, 0);
    ga_unpool1_k<<<8192,256,0,stream>>>(h2, idx2, xg);
    bnstats_k<float><<<dim3(64,4),256,0,stream>>>(xg,64,0,1024, raw_ga);
    bnfin_k<<<1,256,0,stream>>>(raw_ga, mv_ga, 64, 1.f/32768.f);
    ga_out_pm_k<<<4096,256,0,stream>>>(xg, idx1, mv_ga, xatt);

    // ---- MLP residual ---- (p33 region dead again -> pack MLP weights there)
    short* wm1 = (short*)(ws + P33_OFF);             // 512*256
    short* wm2 = wm1 + 512*256;                      // 256*512
    packw_k<<<512,256,0,stream>>>(mlp_w1, wm1, 8, 32);
    packw_k<<<512,256,0,stream>>>(mlp_w2, wm2, 9, 16);
    convmfma_dma_k<4><<<dim3(64,4,32),256,0,stream>>>(xatt,256,0, wm1,256,32, tbuf,512);
    bnstats_pm_k<512><<<dim3(16,32),256,0,stream>>>(tbuf, raw_mlp);
    bnfin_k<<<2,256,0,stream>>>(raw_mlp, mv_mlp, 512, 1.f/131072.f);
    convmfma_reg_k<2,float,4><<<dim3(64,2,32),256,0,stream>>>(tbuf,512,0, mv_mlp, wm2,512,16,
                                                              outp,256,0, x,256,0);
}